// Round 1
// baseline (1359.565 us; speedup 1.0000x reference)
//
#include <hip/hip_runtime.h>
#include <math.h>

// Problem constants
#define BB 128
#define DD 128
#define LSEQ 512
#define HH 8
#define EE 16
#define NMODES 64
#define DFF 512
#define NLAYER 2

__device__ __forceinline__ float4 f4_load(const float* p) { return *(const float4*)p; }
__device__ __forceinline__ void f4_store(float* p, float4 v) { *(float4*)p = v; }
__device__ __forceinline__ float4 f4_zero() { return make_float4(0.f, 0.f, 0.f, 0.f); }
__device__ __forceinline__ void f4_fma(float4& a, float s, const float4 w) {
    a.x += s * w.x; a.y += s * w.y; a.z += s * w.z; a.w += s * w.w;
}
__device__ __forceinline__ float gelu_f(float x) {
    return 0.5f * x * (1.0f + erff(x * 0.70710678118654752440f));
}

// ---------------------------------------------------------------------------
// Init: positional encoding (L x D), forward DFT table Ftt[128][512],
// inverse DFT table G[128][512] (irfft scale folded in).
// Row 2m = cos(2*pi*m*t/512), row 2m+1 = -sin(2*pi*m*t/512).
// ---------------------------------------------------------------------------
__global__ __launch_bounds__(256) void k_init(float* __restrict__ pe,
                                              float* __restrict__ Ftt,
                                              float* __restrict__ G) {
    int idx = blockIdx.x * 256 + threadIdx.x;   // 0..65535
    {
        int l = idx >> 7, d = idx & 127;
        int j = d >> 1;
        double div = exp((double)(2 * j) * (-log(10000.0) / 128.0));
        double a = (double)l * div;
        pe[idx] = (d & 1) ? (float)cos(a) : (float)sin(a);
    }
    {
        int m2 = idx >> 9, t = idx & 511;
        int m = m2 >> 1;
        int r = (m * t) & 511;
        double ang = (double)r * (6.283185307179586476925287 / 512.0);
        float cv = (float)cos(ang), sv = (float)sin(ang);
        float f = (m2 & 1) ? -sv : cv;
        Ftt[idx] = f;
        float s = (m == 0) ? (1.0f / 512.0f) : (2.0f / 512.0f);
        G[idx] = f * s;
    }
}

// ---------------------------------------------------------------------------
// Token embedding: circular conv1d(k=3, D->D) over time + PE.
// h[b,l,d] = sum_i sum_k x_enc[b,i,(l-1+k) mod 512] * cw[d,i,k] + pe[l,d]
// Block: (ltile of 64, b). 256 threads: 32 d-groups(x4) x 8 l-groups(x8).
// ---------------------------------------------------------------------------
__global__ __launch_bounds__(256) void k_embed(const float* __restrict__ xe,
                                               const float* __restrict__ cw,
                                               const float* __restrict__ pe,
                                               float* __restrict__ h) {
    __shared__ float xs[128][66];
    const int b = blockIdx.y, l0 = blockIdx.x * 64;
    for (int idx = threadIdx.x; idx < 128 * 66; idx += 256) {
        int i = idx / 66, t = idx % 66;
        int gl = (l0 - 1 + t) & 511;
        xs[i][t] = xe[(b * 128 + i) * 512 + gl];
    }
    __syncthreads();
    const int dg = threadIdx.x & 31, lg = threadIdx.x >> 5;
    const int d0 = dg * 4;
    float4 acc4[8];
#pragma unroll
    for (int r = 0; r < 8; ++r) acc4[r] = f4_zero();
    for (int i = 0; i < 128; ++i) {
        float xv[10];
#pragma unroll
        for (int t = 0; t < 10; ++t) xv[t] = xs[i][lg * 8 + t];
        const float* wp = cw + ((size_t)d0 * 128 + i) * 3;
        // dj stride in cw = 128*3 = 384
        float4 w0 = make_float4(wp[0], wp[384], wp[768], wp[1152]);
        float4 w1 = make_float4(wp[1], wp[385], wp[769], wp[1153]);
        float4 w2 = make_float4(wp[2], wp[386], wp[770], wp[1154]);
#pragma unroll
        for (int li = 0; li < 8; ++li) {
            f4_fma(acc4[li], xv[li], w0);
            f4_fma(acc4[li], xv[li + 1], w1);
            f4_fma(acc4[li], xv[li + 2], w2);
        }
    }
#pragma unroll
    for (int li = 0; li < 8; ++li) {
        int l = l0 + lg * 8 + li;
        float4 p = f4_load(&pe[l * 128 + d0]);
        float4 o = acc4[li];
        o.x += p.x; o.y += p.y; o.z += p.z; o.w += p.w;
        f4_store(&h[((size_t)b * 512 + l) * 128 + d0], o);
    }
}

// ---------------------------------------------------------------------------
// Generic (B*L,128)x(128,128)+bias GEMM, optional residual add (out = XW+b+R).
// Block: 64 rows. 256 threads: 32 col-groups(x4) x 8 row-groups(x8 rows).
// ---------------------------------------------------------------------------
template <bool RES>
__global__ __launch_bounds__(256) void k_gemm128(const float* __restrict__ X,
                                                 const float* __restrict__ W,
                                                 const float* __restrict__ bias,
                                                 const float* __restrict__ R,
                                                 float* __restrict__ out) {
    __shared__ float xs[64][128];
    const int rowBase = blockIdx.x * 64;
    for (int idx = threadIdx.x; idx < 64 * 32; idx += 256) {
        int r = idx >> 5, c4 = idx & 31;
        f4_store(&xs[r][c4 * 4], f4_load(&X[((size_t)rowBase + r) * 128 + c4 * 4]));
    }
    __syncthreads();
    const int cg = threadIdx.x & 31, rg = threadIdx.x >> 5;
    const int c0 = cg * 4, r0 = rg * 8;
    float4 acc[8];
#pragma unroll
    for (int r = 0; r < 8; ++r) acc[r] = f4_zero();
    for (int k = 0; k < 128; k += 4) {
        float4 w0 = f4_load(&W[(k + 0) * 128 + c0]);
        float4 w1 = f4_load(&W[(k + 1) * 128 + c0]);
        float4 w2 = f4_load(&W[(k + 2) * 128 + c0]);
        float4 w3 = f4_load(&W[(k + 3) * 128 + c0]);
#pragma unroll
        for (int r = 0; r < 8; ++r) {
            float4 x4 = f4_load(&xs[r0 + r][k]);
            f4_fma(acc[r], x4.x, w0); f4_fma(acc[r], x4.y, w1);
            f4_fma(acc[r], x4.z, w2); f4_fma(acc[r], x4.w, w3);
        }
    }
    float4 bv = f4_load(&bias[c0]);
#pragma unroll
    for (int r = 0; r < 8; ++r) {
        float4 o = acc[r];
        o.x += bv.x; o.y += bv.y; o.z += bv.z; o.w += bv.w;
        if (RES) {
            float4 rv = f4_load(&R[((size_t)rowBase + r0 + r) * 128 + c0]);
            o.x += rv.x; o.y += rv.y; o.z += rv.z; o.w += rv.w;
        }
        f4_store(&out[((size_t)rowBase + r0 + r) * 128 + c0], o);
    }
}

// ---------------------------------------------------------------------------
// Forward truncated DFT: c[b,d,m2] = sum_t q[b,t,d] * Ftt[m2][t]
// q is in (B,L,D) layout (d = h*16+e). Block: (m2-tile of 32, b).
// 256 threads: 32 d-groups(x4) x 8 m2-groups(x4).
// ---------------------------------------------------------------------------
__global__ __launch_bounds__(256) void k_fdft(const float* __restrict__ q,
                                              const float* __restrict__ Ftt,
                                              float* __restrict__ cbuf) {
    __shared__ float fs[32][512];
    const int b = blockIdx.y, m2b = blockIdx.x * 32;
    for (int idx = threadIdx.x; idx < 32 * 128; idx += 256) {
        int r = idx >> 7, c4 = idx & 127;
        f4_store(&fs[r][c4 * 4], f4_load(&Ftt[(m2b + r) * 512 + c4 * 4]));
    }
    __syncthreads();
    const int dg = threadIdx.x & 31, mg = threadIdx.x >> 5;
    const int d0 = dg * 4, m0 = mg * 4;
    float4 acc4[4];  // [mj], components = dj
#pragma unroll
    for (int m = 0; m < 4; ++m) acc4[m] = f4_zero();
    for (int t = 0; t < 512; t += 4) {
        float4 q0 = f4_load(&q[((size_t)b * 512 + t + 0) * 128 + d0]);
        float4 q1 = f4_load(&q[((size_t)b * 512 + t + 1) * 128 + d0]);
        float4 q2 = f4_load(&q[((size_t)b * 512 + t + 2) * 128 + d0]);
        float4 q3 = f4_load(&q[((size_t)b * 512 + t + 3) * 128 + d0]);
#pragma unroll
        for (int mj = 0; mj < 4; ++mj) {
            float4 f = f4_load(&fs[m0 + mj][t]);
            f4_fma(acc4[mj], f.x, q0); f4_fma(acc4[mj], f.y, q1);
            f4_fma(acc4[mj], f.z, q2); f4_fma(acc4[mj], f.w, q3);
        }
    }
    // transpose write: c[b, d0+dj, m2b+m0 .. +3]
    f4_store(&cbuf[((size_t)b * 128 + d0 + 0) * 128 + m2b + m0],
             make_float4(acc4[0].x, acc4[1].x, acc4[2].x, acc4[3].x));
    f4_store(&cbuf[((size_t)b * 128 + d0 + 1) * 128 + m2b + m0],
             make_float4(acc4[0].y, acc4[1].y, acc4[2].y, acc4[3].y));
    f4_store(&cbuf[((size_t)b * 128 + d0 + 2) * 128 + m2b + m0],
             make_float4(acc4[0].z, acc4[1].z, acc4[2].z, acc4[3].z));
    f4_store(&cbuf[((size_t)b * 128 + d0 + 3) * 128 + m2b + m0],
             make_float4(acc4[0].w, acc4[1].w, acc4[2].w, acc4[3].w));
}

// ---------------------------------------------------------------------------
// Mode mix: per (b,h,m): complex 16-vec x complex 16x16 matrix.
// dr[o,m] = sum_e cr*fwr - ci*fwi ; di[o,m] = sum_e cr*fwi + ci*fwr
// c layout: (B, 128=h*16+e, 128=2m|2m+1). dd same layout over o.
// Block: (h, b). 256 threads: 64 m x 4 o-groups(x4).
// ---------------------------------------------------------------------------
__global__ __launch_bounds__(256) void k_mix(const float* __restrict__ cbuf,
                                             const float* __restrict__ fwr,
                                             const float* __restrict__ fwi,
                                             float* __restrict__ dd) {
    __shared__ float cs[16][128];
    const int hh = blockIdx.x, b = blockIdx.y;
    for (int idx = threadIdx.x; idx < 16 * 32; idx += 256) {
        int e = idx >> 5, c4 = idx & 31;
        f4_store(&cs[e][c4 * 4],
                 f4_load(&cbuf[((size_t)b * 128 + hh * 16 + e) * 128 + c4 * 4]));
    }
    __syncthreads();
    const int m = threadIdx.x & 63, og = threadIdx.x >> 6;
    float dr[4] = {0.f, 0.f, 0.f, 0.f}, di[4] = {0.f, 0.f, 0.f, 0.f};
    for (int e = 0; e < 16; ++e) {
        float2 cv = *(const float2*)&cs[e][2 * m];
#pragma unroll
        for (int oi = 0; oi < 4; ++oi) {
            int o = og * 4 + oi;
            float wr = fwr[(((size_t)hh * 16 + e) * 16 + o) * 64 + m];
            float wi = fwi[(((size_t)hh * 16 + e) * 16 + o) * 64 + m];
            dr[oi] += cv.x * wr - cv.y * wi;
            di[oi] += cv.x * wi + cv.y * wr;
        }
    }
#pragma unroll
    for (int oi = 0; oi < 4; ++oi) {
        int o = og * 4 + oi;
        float2 v = make_float2(dr[oi], di[oi]);
        *(float2*)&dd[((size_t)b * 128 + hh * 16 + o) * 128 + 2 * m] = v;
    }
}

// ---------------------------------------------------------------------------
// Inverse truncated DFT: y[b,ho,t] = sum_m2 dd[b,ho,m2] * G[m2][t]
// Output written in (B, H*E, L) contiguous order (the reference's flat
// reshape quirk). Block: (t-tile of 64, b). Threads: 32 hog x 8 tg.
// Thread covers ho = hog + 32*hj (conflict-free with stride-65 LDS) x 8 t.
// dd staged in two 64-mode halves to fit 33.3 KB LDS.
// ---------------------------------------------------------------------------
__global__ __launch_bounds__(256) void k_idft(const float* __restrict__ dd,
                                              const float* __restrict__ G,
                                              float* __restrict__ y) {
    __shared__ float ds[128][65];
    const int b = blockIdx.y, t0 = blockIdx.x * 64;
    const int hog = threadIdx.x & 31, tg = threadIdx.x >> 5;
    const int tb = tg * 8;
    float4 acc4[8];  // [ti], components = hj (ho = hog + 32*hj)
#pragma unroll
    for (int t = 0; t < 8; ++t) acc4[t] = f4_zero();
    for (int half = 0; half < 2; ++half) {
        if (half) __syncthreads();
        for (int idx = threadIdx.x; idx < 128 * 16; idx += 256) {
            int ho = idx >> 4, c4 = idx & 15;
            float4 v = f4_load(&dd[((size_t)b * 128 + ho) * 128 + half * 64 + c4 * 4]);
            ds[ho][c4 * 4 + 0] = v.x; ds[ho][c4 * 4 + 1] = v.y;
            ds[ho][c4 * 4 + 2] = v.z; ds[ho][c4 * 4 + 3] = v.w;
        }
        __syncthreads();
        for (int m2l = 0; m2l < 64; ++m2l) {
            int m2 = half * 64 + m2l;
            float4 dvec = make_float4(ds[hog][m2l], ds[hog + 32][m2l],
                                      ds[hog + 64][m2l], ds[hog + 96][m2l]);
            float4 g0 = f4_load(&G[(size_t)m2 * 512 + t0 + tb]);
            float4 g1 = f4_load(&G[(size_t)m2 * 512 + t0 + tb + 4]);
            f4_fma(acc4[0], g0.x, dvec); f4_fma(acc4[1], g0.y, dvec);
            f4_fma(acc4[2], g0.z, dvec); f4_fma(acc4[3], g0.w, dvec);
            f4_fma(acc4[4], g1.x, dvec); f4_fma(acc4[5], g1.y, dvec);
            f4_fma(acc4[6], g1.z, dvec); f4_fma(acc4[7], g1.w, dvec);
        }
    }
    f4_store(&y[((size_t)b * 128 + hog + 0) * 512 + t0 + tb],
             make_float4(acc4[0].x, acc4[1].x, acc4[2].x, acc4[3].x));
    f4_store(&y[((size_t)b * 128 + hog + 0) * 512 + t0 + tb + 4],
             make_float4(acc4[4].x, acc4[5].x, acc4[6].x, acc4[7].x));
    f4_store(&y[((size_t)b * 128 + hog + 32) * 512 + t0 + tb],
             make_float4(acc4[0].y, acc4[1].y, acc4[2].y, acc4[3].y));
    f4_store(&y[((size_t)b * 128 + hog + 32) * 512 + t0 + tb + 4],
             make_float4(acc4[4].y, acc4[5].y, acc4[6].y, acc4[7].y));
    f4_store(&y[((size_t)b * 128 + hog + 64) * 512 + t0 + tb],
             make_float4(acc4[0].z, acc4[1].z, acc4[2].z, acc4[3].z));
    f4_store(&y[((size_t)b * 128 + hog + 64) * 512 + t0 + tb + 4],
             make_float4(acc4[4].z, acc4[5].z, acc4[6].z, acc4[7].z));
    f4_store(&y[((size_t)b * 128 + hog + 96) * 512 + t0 + tb],
             make_float4(acc4[0].w, acc4[1].w, acc4[2].w, acc4[3].w));
    f4_store(&y[((size_t)b * 128 + hog + 96) * 512 + t0 + tb + 4],
             make_float4(acc4[4].w, acc4[5].w, acc4[6].w, acc4[7].w));
}

// ---------------------------------------------------------------------------
// Series decomp: out = x - movmean(x, 25) along time, replicate padding.
// Block: (l-tile of 64, b); stages rows l0-12 .. l0+75 (clamped).
// Threads: 32 d-groups(float4) x 8 l-groups(x8, sliding window).
// ---------------------------------------------------------------------------
__global__ __launch_bounds__(256) void k_decomp(const float* __restrict__ X,
                                                float* __restrict__ out) {
    __shared__ float xs[88][128];
    const int b = blockIdx.y, l0 = blockIdx.x * 64;
    for (int idx = threadIdx.x; idx < 88 * 32; idx += 256) {
        int r = idx >> 5, c4 = idx & 31;
        int gl = l0 - 12 + r;
        gl = gl < 0 ? 0 : (gl > 511 ? 511 : gl);
        f4_store(&xs[r][c4 * 4], f4_load(&X[((size_t)b * 512 + gl) * 128 + c4 * 4]));
    }
    __syncthreads();
    const int dg = threadIdx.x & 31, lg = threadIdx.x >> 5;
    const int d0 = dg * 4, base = lg * 8;
    float4 s = f4_zero();
#pragma unroll
    for (int w = 0; w < 25; ++w) {
        float4 v = f4_load(&xs[base + w][d0]);
        s.x += v.x; s.y += v.y; s.z += v.z; s.w += v.w;
    }
    const float inv = 1.0f / 25.0f;
#pragma unroll
    for (int i = 0; i < 8; ++i) {
        int t = base + 12 + i;
        float4 x = f4_load(&xs[t][d0]);
        float4 o = make_float4(x.x - s.x * inv, x.y - s.y * inv,
                               x.z - s.z * inv, x.w - s.w * inv);
        f4_store(&out[((size_t)b * 512 + l0 + lg * 8 + i) * 128 + d0], o);
        if (i < 7) {
            float4 a = f4_load(&xs[base + 25 + i][d0]);
            float4 r = f4_load(&xs[base + i][d0]);
            s.x += a.x - r.x; s.y += a.y - r.y; s.z += a.z - r.z; s.w += a.w - r.w;
        }
    }
}

// ---------------------------------------------------------------------------
// Fused FFN: out = x + gelu(x @ W1) @ W2  (no biases). Block: 64 rows.
// Intermediate (64 x 512) processed in 4 chunks of 128 through LDS.
// ---------------------------------------------------------------------------
__global__ __launch_bounds__(256) void k_ffn(const float* __restrict__ X,
                                             const float* __restrict__ W1,
                                             const float* __restrict__ W2,
                                             float* __restrict__ out) {
    __shared__ float xs[64][128];
    __shared__ float ts[64][128];
    const int rowBase = blockIdx.x * 64;
    for (int idx = threadIdx.x; idx < 64 * 32; idx += 256) {
        int r = idx >> 5, c4 = idx & 31;
        f4_store(&xs[r][c4 * 4], f4_load(&X[((size_t)rowBase + r) * 128 + c4 * 4]));
    }
    __syncthreads();
    const int cg = threadIdx.x & 31, rg = threadIdx.x >> 5;
    const int c0 = cg * 4, r0 = rg * 8;
    float4 acc2[8];
#pragma unroll
    for (int r = 0; r < 8; ++r) acc2[r] = f4_zero();
    for (int f0 = 0; f0 < DFF; f0 += 128) {
        float4 ta[8];
#pragma unroll
        for (int r = 0; r < 8; ++r) ta[r] = f4_zero();
        for (int k = 0; k < 128; k += 4) {
            float4 w0 = f4_load(&W1[(k + 0) * DFF + f0 + c0]);
            float4 w1 = f4_load(&W1[(k + 1) * DFF + f0 + c0]);
            float4 w2 = f4_load(&W1[(k + 2) * DFF + f0 + c0]);
            float4 w3 = f4_load(&W1[(k + 3) * DFF + f0 + c0]);
#pragma unroll
            for (int r = 0; r < 8; ++r) {
                float4 x4 = f4_load(&xs[r0 + r][k]);
                f4_fma(ta[r], x4.x, w0); f4_fma(ta[r], x4.y, w1);
                f4_fma(ta[r], x4.z, w2); f4_fma(ta[r], x4.w, w3);
            }
        }
#pragma unroll
        for (int r = 0; r < 8; ++r) {
            float4 g = make_float4(gelu_f(ta[r].x), gelu_f(ta[r].y),
                                   gelu_f(ta[r].z), gelu_f(ta[r].w));
            f4_store(&ts[r0 + r][c0], g);
        }
        __syncthreads();
        for (int k = 0; k < 128; k += 4) {
            float4 w0 = f4_load(&W2[(f0 + k + 0) * 128 + c0]);
            float4 w1 = f4_load(&W2[(f0 + k + 1) * 128 + c0]);
            float4 w2 = f4_load(&W2[(f0 + k + 2) * 128 + c0]);
            float4 w3 = f4_load(&W2[(f0 + k + 3) * 128 + c0]);
#pragma unroll
            for (int r = 0; r < 8; ++r) {
                float4 t4 = f4_load(&ts[r0 + r][k]);
                f4_fma(acc2[r], t4.x, w0); f4_fma(acc2[r], t4.y, w1);
                f4_fma(acc2[r], t4.z, w2); f4_fma(acc2[r], t4.w, w3);
            }
        }
        __syncthreads();
    }
#pragma unroll
    for (int r = 0; r < 8; ++r) {
        float4 xres = f4_load(&xs[r0 + r][c0]);
        float4 o = acc2[r];
        o.x += xres.x; o.y += xres.y; o.z += xres.z; o.w += xres.w;
        f4_store(&out[((size_t)rowBase + r0 + r) * 128 + c0], o);
    }
}

// ---------------------------------------------------------------------------
// LayerNorm over features (D=128). One wave per row, 4 rows per block.
// ---------------------------------------------------------------------------
__global__ __launch_bounds__(256) void k_ln(const float* __restrict__ X,
                                            const float* __restrict__ g,
                                            const float* __restrict__ bb,
                                            float* __restrict__ out) {
    const int row = blockIdx.x * 4 + (threadIdx.x >> 6);
    const int lane = threadIdx.x & 63;
    float2 v = *(const float2*)&X[(size_t)row * 128 + lane * 2];
    float s = v.x + v.y, ss = v.x * v.x + v.y * v.y;
#pragma unroll
    for (int o = 32; o; o >>= 1) {
        s += __shfl_xor(s, o);
        ss += __shfl_xor(ss, o);
    }
    float mu = s * (1.0f / 128.0f);
    float var = ss * (1.0f / 128.0f) - mu * mu;
    float rstd = rsqrtf(var + 1e-5f);
    float2 gg = *(const float2*)&g[lane * 2];
    float2 bv = *(const float2*)&bb[lane * 2];
    float2 o;
    o.x = (v.x - mu) * rstd * gg.x + bv.x;
    o.y = (v.y - mu) * rstd * gg.y + bv.y;
    *(float2*)&out[(size_t)row * 128 + lane * 2] = o;
}

// Column (time) sums for the my_Layernorm mean-over-time subtraction.
__global__ __launch_bounds__(128) void k_colmean(const float* __restrict__ X,
                                                 float* __restrict__ cm) {
    const int b = blockIdx.y, l0 = blockIdx.x * 64, d = threadIdx.x;
    float s = 0.f;
    for (int l = l0; l < l0 + 64; ++l) s += X[((size_t)b * 512 + l) * 128 + d];
    atomicAdd(&cm[b * 128 + d], s);
}

// Final: gelu(hn - colmean/512) * mark, dot with proj_w, + proj_b.
__global__ __launch_bounds__(128) void k_final(const float* __restrict__ hn,
                                               const float* __restrict__ cm,
                                               const float* __restrict__ mark,
                                               const float* __restrict__ pw,
                                               const float* __restrict__ pb,
                                               float* __restrict__ out) {
    const int b = blockIdx.y, l0 = blockIdx.x * 128, d = threadIdx.x;
    const float c = cm[b * 128 + d] * (1.0f / 512.0f);
    float acc = 0.f;
    for (int l = l0; l < l0 + 128; ++l) {
        float v = hn[((size_t)b * 512 + l) * 128 + d] - c;
        acc += gelu_f(v) * mark[((size_t)b * 128 + d) * 512 + l] * pw[l * 128 + d];
    }
    __shared__ float red[2];
#pragma unroll
    for (int o = 32; o; o >>= 1) acc += __shfl_xor(acc, o);
    if ((threadIdx.x & 63) == 0) red[threadIdx.x >> 6] = acc;
    __syncthreads();
    if (threadIdx.x == 0) {
        float tot = red[0] + red[1];
        if (blockIdx.x == 0) tot += pb[0];
        atomicAdd(&out[b], tot);
    }
}

// ---------------------------------------------------------------------------
extern "C" void kernel_launch(void* const* d_in, const int* in_sizes, int n_in,
                              void* d_out, int out_size, void* d_ws, size_t ws_size,
                              hipStream_t stream) {
    const float* xe   = (const float*)d_in[0];
    const float* mark = (const float*)d_in[1];
    const float* cw   = (const float*)d_in[4];
    const float* Wq   = (const float*)d_in[5];
    const float* bq   = (const float*)d_in[6];
    const float* Wo   = (const float*)d_in[7];
    const float* bo   = (const float*)d_in[8];
    const float* fwr  = (const float*)d_in[9];
    const float* fwi  = (const float*)d_in[10];
    const float* W1   = (const float*)d_in[11];
    const float* W2   = (const float*)d_in[12];
    const float* lng  = (const float*)d_in[13];
    const float* lnb  = (const float*)d_in[14];
    const float* pw   = (const float*)d_in[15];
    const float* pb   = (const float*)d_in[16];
    float* out = (float*)d_out;

    float* ws  = (float*)d_ws;
    float* pe  = ws;                  // 65536
    float* Ftt = ws + 65536;          // 65536
    float* G   = ws + 131072;         // 65536
    float* h   = ws + 196608;         // 8388608
    float* b1  = h + 8388608;         // 8388608
    float* b2  = b1 + 8388608;        // 8388608 (c at +0, dd at +2097152)
    float* cm  = b2 + 8388608;        // 16384
    // total: 25378816 floats = 101.5 MB

    k_init<<<256, 256, 0, stream>>>(pe, Ftt, G);
    k_embed<<<dim3(8, 128), 256, 0, stream>>>(xe, cw, pe, h);
    for (int l = 0; l < NLAYER; ++l) {
        k_gemm128<false><<<1024, 256, 0, stream>>>(h, Wq + l * 16384, bq + l * 128,
                                                   nullptr, b1);
        k_fdft<<<dim3(4, 128), 256, 0, stream>>>(b1, Ftt, b2);
        k_mix<<<dim3(8, 128), 256, 0, stream>>>(b2, fwr + l * 131072,
                                                fwi + l * 131072, b2 + 2097152);
        k_idft<<<dim3(8, 128), 256, 0, stream>>>(b2 + 2097152, G, b1);
        k_gemm128<true><<<1024, 256, 0, stream>>>(b1, Wo + l * 16384, bo + l * 128,
                                                  h, b2);
        k_decomp<<<dim3(8, 128), 256, 0, stream>>>(b2, h);
        k_ffn<<<1024, 256, 0, stream>>>(h, W1 + l * 65536, W2 + l * 65536, b2);
        k_decomp<<<dim3(8, 128), 256, 0, stream>>>(b2, h);
    }
    k_ln<<<16384, 256, 0, stream>>>(h, lng, lnb, b1);
    hipMemsetAsync(cm, 0, 16384 * sizeof(float), stream);
    k_colmean<<<dim3(8, 128), 128, 0, stream>>>(b1, cm);
    hipMemsetAsync(d_out, 0, 128 * sizeof(float), stream);
    k_final<<<dim3(4, 128), 128, 0, stream>>>(b1, cm, mark, pw, pb, out);

    (void)in_sizes; (void)n_in; (void)out_size; (void)ws_size;
}

// Round 2
// 943.663 us; speedup vs baseline: 1.4407x; 1.4407x over previous
//
#include <hip/hip_runtime.h>
#include <math.h>

#define DFF 512
#define NLAYER 2

typedef __bf16 bf16x8 __attribute__((ext_vector_type(8)));
typedef float f32x4 __attribute__((ext_vector_type(4)));

__device__ __forceinline__ float4 f4_load(const float* p) { return *(const float4*)p; }
__device__ __forceinline__ void f4_store(float* p, float4 v) { *(float4*)p = v; }
__device__ __forceinline__ float4 f4_zero() { return make_float4(0.f, 0.f, 0.f, 0.f); }
__device__ __forceinline__ void f4_fma(float4& a, float s, const float4 w) {
    a.x += s * w.x; a.y += s * w.y; a.z += s * w.z; a.w += s * w.w;
}
__device__ __forceinline__ float gelu_f(float x) {
    return 0.5f * x * (1.0f + erff(x * 0.70710678118654752440f));
}
// XOR-swizzled LDS offset for a 128-elem bf16 row (16B-group swizzle, no pad).
__device__ __forceinline__ int sw_off(int r, int c) {
    return (r << 7) + (((c >> 3) ^ (r & 7)) << 3) + (c & 7);
}
__device__ __forceinline__ void store_bf4(__bf16* p, float4 v) {
    __bf16 t[4] = {(__bf16)v.x, (__bf16)v.y, (__bf16)v.z, (__bf16)v.w};
    *(uint2*)p = *(uint2*)t;
}

// ---------------------------------------------------------------------------
// Init: positional encoding, forward DFT table Ftt[128][512], inverse G.
// ---------------------------------------------------------------------------
__global__ __launch_bounds__(256) void k_init(float* __restrict__ pe,
                                              float* __restrict__ Ftt,
                                              float* __restrict__ G) {
    int idx = blockIdx.x * 256 + threadIdx.x;   // 0..65535
    {
        int l = idx >> 7, d = idx & 127;
        int j = d >> 1;
        double div = exp((double)(2 * j) * (-log(10000.0) / 128.0));
        double a = (double)l * div;
        pe[idx] = (d & 1) ? (float)cos(a) : (float)sin(a);
    }
    {
        int m2 = idx >> 9, t = idx & 511;
        int m = m2 >> 1;
        int r = (m * t) & 511;
        double ang = (double)r * (6.283185307179586476925287 / 512.0);
        float cv = (float)cos(ang), sv = (float)sin(ang);
        float f = (m2 & 1) ? -sv : cv;
        Ftt[idx] = f;
        float s = (m == 0) ? (1.0f / 512.0f) : (2.0f / 512.0f);
        G[idx] = f * s;
    }
}

// ---------------------------------------------------------------------------
// Cast+transpose weights to bf16: Wqt/Wot (n-major 128x128), W1t[f][k], W2t[n][f]
// ---------------------------------------------------------------------------
__global__ __launch_bounds__(256) void k_castw(const float* __restrict__ Wq,
                                               const float* __restrict__ Wo,
                                               const float* __restrict__ W1,
                                               const float* __restrict__ W2,
                                               __bf16* __restrict__ wbf) {
    int i = blockIdx.x * 256 + threadIdx.x;   // < 327680
    if (i < 65536) {
        int r = i & 16383, l = (i >> 14) & 1;
        int n = r >> 7, k = r & 127;
        const float* W = (i >= 32768) ? Wo : Wq;
        wbf[i] = (__bf16)W[l * 16384 + k * 128 + n];
    } else if (i < 196608) {
        int j = i - 65536;
        int l = j >> 16, r = j & 65535;
        int f = r >> 7, k = r & 127;
        wbf[i] = (__bf16)W1[l * 65536 + k * 512 + f];
    } else if (i < 327680) {
        int j = i - 196608;
        int l = j >> 16, r = j & 65535;
        int n = r >> 9, f = r & 511;
        wbf[i] = (__bf16)W2[l * 65536 + f * 128 + n];
    }
}

// ---------------------------------------------------------------------------
// Token embedding: circular conv1d(k=3) + PE. Writes fp32 h and bf16 shadow.
// ---------------------------------------------------------------------------
__global__ __launch_bounds__(256) void k_embed(const float* __restrict__ xe,
                                               const float* __restrict__ cw,
                                               const float* __restrict__ pe,
                                               float* __restrict__ h,
                                               __bf16* __restrict__ hb) {
    __shared__ float xs[128][66];
    const int b = blockIdx.y, l0 = blockIdx.x * 64;
    for (int idx = threadIdx.x; idx < 128 * 66; idx += 256) {
        int i = idx / 66, t = idx % 66;
        int gl = (l0 - 1 + t) & 511;
        xs[i][t] = xe[(b * 128 + i) * 512 + gl];
    }
    __syncthreads();
    const int dg = threadIdx.x & 31, lg = threadIdx.x >> 5;
    const int d0 = dg * 4;
    float4 acc4[8];
#pragma unroll
    for (int r = 0; r < 8; ++r) acc4[r] = f4_zero();
    for (int i = 0; i < 128; ++i) {
        float xv[10];
#pragma unroll
        for (int t = 0; t < 10; ++t) xv[t] = xs[i][lg * 8 + t];
        const float* wp = cw + ((size_t)d0 * 128 + i) * 3;
        float4 w0 = make_float4(wp[0], wp[384], wp[768], wp[1152]);
        float4 w1 = make_float4(wp[1], wp[385], wp[769], wp[1153]);
        float4 w2 = make_float4(wp[2], wp[386], wp[770], wp[1154]);
#pragma unroll
        for (int li = 0; li < 8; ++li) {
            f4_fma(acc4[li], xv[li], w0);
            f4_fma(acc4[li], xv[li + 1], w1);
            f4_fma(acc4[li], xv[li + 2], w2);
        }
    }
#pragma unroll
    for (int li = 0; li < 8; ++li) {
        int l = l0 + lg * 8 + li;
        float4 p = f4_load(&pe[l * 128 + d0]);
        float4 o = acc4[li];
        o.x += p.x; o.y += p.y; o.z += p.z; o.w += p.w;
        size_t idx = ((size_t)b * 512 + l) * 128 + d0;
        f4_store(&h[idx], o);
        store_bf4(&hb[idx], o);
    }
}

// ---------------------------------------------------------------------------
// MFMA GEMM: out(M x 128 fp32) = Xb(M x 128 bf16) @ W(128x128) + bias (+R).
// Wt is n-major bf16 (Wt[n][k]). Block = 128 rows, 4 waves in 2x2 (64x64 each).
// ---------------------------------------------------------------------------
template <bool RES>
__global__ __launch_bounds__(256) void k_mgemm(const __bf16* __restrict__ Xb,
                                               const __bf16* __restrict__ Wt,
                                               const float* __restrict__ bias,
                                               const float* __restrict__ R,
                                               float* __restrict__ out) {
    __shared__ __align__(16) __bf16 xs[128 * 128];
    const int rowBase = blockIdx.x * 128;
#pragma unroll
    for (int i = 0; i < 8; ++i) {
        int c = i * 256 + threadIdx.x;          // 16B chunk id, 0..2047
        int r = c >> 4, g = c & 15;
        *(uint4*)&xs[(r << 7) + ((g ^ (r & 7)) << 3)] =
            *(const uint4*)&Xb[(((size_t)rowBase + r) << 7) + (g << 3)];
    }
    __syncthreads();
    const int lane = threadIdx.x & 63, wid = threadIdx.x >> 6;
    const int wrow = (wid & 1) * 64, wcol = (wid >> 1) * 64;
    const int m16 = lane & 15, quad = lane >> 4;
    f32x4 acc[4][4];
#pragma unroll
    for (int a = 0; a < 4; ++a)
#pragma unroll
        for (int b = 0; b < 4; ++b) acc[a][b] = {0.f, 0.f, 0.f, 0.f};
#pragma unroll
    for (int ks = 0; ks < 4; ++ks) {
        const int ko = ks * 32 + quad * 8;
        const int xg = (((ks * 4 + quad) ^ (m16 & 7)) << 3);
        bf16x8 af[4], bfr[4];
#pragma unroll
        for (int rt = 0; rt < 4; ++rt)
            af[rt] = *(const bf16x8*)&xs[((wrow + rt * 16 + m16) << 7) + xg];
#pragma unroll
        for (int ct = 0; ct < 4; ++ct)
            bfr[ct] = *(const bf16x8*)&Wt[((size_t)(wcol + ct * 16 + m16) << 7) + ko];
#pragma unroll
        for (int rt = 0; rt < 4; ++rt)
#pragma unroll
            for (int ct = 0; ct < 4; ++ct)
                acc[rt][ct] = __builtin_amdgcn_mfma_f32_16x16x32_bf16(
                    af[rt], bfr[ct], acc[rt][ct], 0, 0, 0);
    }
#pragma unroll
    for (int ct = 0; ct < 4; ++ct) {
        int gcol = wcol + ct * 16 + m16;
        float bv = bias[gcol];
#pragma unroll
        for (int rt = 0; rt < 4; ++rt)
#pragma unroll
            for (int r = 0; r < 4; ++r) {
                size_t gi = ((size_t)(rowBase + wrow + rt * 16 + quad * 4 + r) << 7) + gcol;
                float v = acc[rt][ct][r] + bv;
                if (RES) v += R[gi];
                out[gi] = v;
            }
    }
}

// ---------------------------------------------------------------------------
// MFMA FFN: out = Xf + gelu(X @ W1) @ W2. Chunks of 128 over DFF through LDS.
// ---------------------------------------------------------------------------
__global__ __launch_bounds__(256) void k_ffnm(const __bf16* __restrict__ Xb,
                                              const float* __restrict__ Xf,
                                              const __bf16* __restrict__ W1t,
                                              const __bf16* __restrict__ W2t,
                                              float* __restrict__ out) {
    __shared__ __align__(16) __bf16 xs[128 * 128];
    __shared__ __align__(16) __bf16 ts[128 * 128];
    const int rowBase = blockIdx.x * 128;
#pragma unroll
    for (int i = 0; i < 8; ++i) {
        int c = i * 256 + threadIdx.x;
        int r = c >> 4, g = c & 15;
        *(uint4*)&xs[(r << 7) + ((g ^ (r & 7)) << 3)] =
            *(const uint4*)&Xb[(((size_t)rowBase + r) << 7) + (g << 3)];
    }
    __syncthreads();
    const int lane = threadIdx.x & 63, wid = threadIdx.x >> 6;
    const int wrow = (wid & 1) * 64, wcol = (wid >> 1) * 64;
    const int m16 = lane & 15, quad = lane >> 4;
    f32x4 acc2[4][4];
#pragma unroll
    for (int a = 0; a < 4; ++a)
#pragma unroll
        for (int b = 0; b < 4; ++b) acc2[a][b] = {0.f, 0.f, 0.f, 0.f};

    for (int f0 = 0; f0 < DFF; f0 += 128) {
        f32x4 c1[4][4];
#pragma unroll
        for (int a = 0; a < 4; ++a)
#pragma unroll
            for (int b = 0; b < 4; ++b) c1[a][b] = {0.f, 0.f, 0.f, 0.f};
#pragma unroll
        for (int ks = 0; ks < 4; ++ks) {
            const int ko = ks * 32 + quad * 8;
            const int xg = (((ks * 4 + quad) ^ (m16 & 7)) << 3);
            bf16x8 af[4], bfr[4];
#pragma unroll
            for (int rt = 0; rt < 4; ++rt)
                af[rt] = *(const bf16x8*)&xs[((wrow + rt * 16 + m16) << 7) + xg];
#pragma unroll
            for (int ct = 0; ct < 4; ++ct)
                bfr[ct] = *(const bf16x8*)&W1t[((size_t)(f0 + wcol + ct * 16 + m16) << 7) + ko];
#pragma unroll
            for (int rt = 0; rt < 4; ++rt)
#pragma unroll
                for (int ct = 0; ct < 4; ++ct)
                    c1[rt][ct] = __builtin_amdgcn_mfma_f32_16x16x32_bf16(
                        af[rt], bfr[ct], c1[rt][ct], 0, 0, 0);
        }
        // gelu -> bf16 -> ts (C/D layout scatter, swizzled)
#pragma unroll
        for (int rt = 0; rt < 4; ++rt)
#pragma unroll
            for (int ct = 0; ct < 4; ++ct)
#pragma unroll
                for (int r = 0; r < 4; ++r) {
                    int lrow = wrow + rt * 16 + quad * 4 + r;
                    int lcol = wcol + ct * 16 + m16;
                    ts[sw_off(lrow, lcol)] = (__bf16)gelu_f(c1[rt][ct][r]);
                }
        __syncthreads();
#pragma unroll
        for (int ks = 0; ks < 4; ++ks) {
            const int ko = ks * 32 + quad * 8;
            const int xg = (((ks * 4 + quad) ^ (m16 & 7)) << 3);
            bf16x8 af[4], bfr[4];
#pragma unroll
            for (int rt = 0; rt < 4; ++rt)
                af[rt] = *(const bf16x8*)&ts[((wrow + rt * 16 + m16) << 7) + xg];
#pragma unroll
            for (int ct = 0; ct < 4; ++ct)
                bfr[ct] = *(const bf16x8*)&W2t[((size_t)(wcol + ct * 16 + m16) << 9) + f0 + ko];
#pragma unroll
            for (int rt = 0; rt < 4; ++rt)
#pragma unroll
                for (int ct = 0; ct < 4; ++ct)
                    acc2[rt][ct] = __builtin_amdgcn_mfma_f32_16x16x32_bf16(
                        af[rt], bfr[ct], acc2[rt][ct], 0, 0, 0);
        }
        __syncthreads();
    }
#pragma unroll
    for (int ct = 0; ct < 4; ++ct) {
        int gcol = wcol + ct * 16 + m16;
#pragma unroll
        for (int rt = 0; rt < 4; ++rt)
#pragma unroll
            for (int r = 0; r < 4; ++r) {
                size_t gi = ((size_t)(rowBase + wrow + rt * 16 + quad * 4 + r) << 7) + gcol;
                out[gi] = acc2[rt][ct][r] + Xf[gi];
            }
    }
}

// ---------------------------------------------------------------------------
// Forward truncated DFT (fp32): c[b,d,m2] = sum_t q[b,t,d] * Ftt[m2][t]
// ---------------------------------------------------------------------------
__global__ __launch_bounds__(256) void k_fdft(const float* __restrict__ q,
                                              const float* __restrict__ Ftt,
                                              float* __restrict__ cbuf) {
    __shared__ float fs[32][512];
    const int b = blockIdx.y, m2b = blockIdx.x * 32;
    for (int idx = threadIdx.x; idx < 32 * 128; idx += 256) {
        int r = idx >> 7, c4 = idx & 127;
        f4_store(&fs[r][c4 * 4], f4_load(&Ftt[(m2b + r) * 512 + c4 * 4]));
    }
    __syncthreads();
    const int dg = threadIdx.x & 31, mg = threadIdx.x >> 5;
    const int d0 = dg * 4, m0 = mg * 4;
    float4 acc4[4];
#pragma unroll
    for (int m = 0; m < 4; ++m) acc4[m] = f4_zero();
    for (int t = 0; t < 512; t += 4) {
        float4 q0 = f4_load(&q[((size_t)b * 512 + t + 0) * 128 + d0]);
        float4 q1 = f4_load(&q[((size_t)b * 512 + t + 1) * 128 + d0]);
        float4 q2 = f4_load(&q[((size_t)b * 512 + t + 2) * 128 + d0]);
        float4 q3 = f4_load(&q[((size_t)b * 512 + t + 3) * 128 + d0]);
#pragma unroll
        for (int mj = 0; mj < 4; ++mj) {
            float4 f = f4_load(&fs[m0 + mj][t]);
            f4_fma(acc4[mj], f.x, q0); f4_fma(acc4[mj], f.y, q1);
            f4_fma(acc4[mj], f.z, q2); f4_fma(acc4[mj], f.w, q3);
        }
    }
    f4_store(&cbuf[((size_t)b * 128 + d0 + 0) * 128 + m2b + m0],
             make_float4(acc4[0].x, acc4[1].x, acc4[2].x, acc4[3].x));
    f4_store(&cbuf[((size_t)b * 128 + d0 + 1) * 128 + m2b + m0],
             make_float4(acc4[0].y, acc4[1].y, acc4[2].y, acc4[3].y));
    f4_store(&cbuf[((size_t)b * 128 + d0 + 2) * 128 + m2b + m0],
             make_float4(acc4[0].z, acc4[1].z, acc4[2].z, acc4[3].z));
    f4_store(&cbuf[((size_t)b * 128 + d0 + 3) * 128 + m2b + m0],
             make_float4(acc4[0].w, acc4[1].w, acc4[2].w, acc4[3].w));
}

// ---------------------------------------------------------------------------
// Mode mix (fp32, tiny): complex 16-vec x 16x16 per (b,h,m).
// ---------------------------------------------------------------------------
__global__ __launch_bounds__(256) void k_mix(const float* __restrict__ cbuf,
                                             const float* __restrict__ fwr,
                                             const float* __restrict__ fwi,
                                             float* __restrict__ dd) {
    __shared__ float cs[16][128];
    const int hh = blockIdx.x, b = blockIdx.y;
    for (int idx = threadIdx.x; idx < 16 * 32; idx += 256) {
        int e = idx >> 5, c4 = idx & 31;
        f4_store(&cs[e][c4 * 4],
                 f4_load(&cbuf[((size_t)b * 128 + hh * 16 + e) * 128 + c4 * 4]));
    }
    __syncthreads();
    const int m = threadIdx.x & 63, og = threadIdx.x >> 6;
    float dr[4] = {0.f, 0.f, 0.f, 0.f}, di[4] = {0.f, 0.f, 0.f, 0.f};
    for (int e = 0; e < 16; ++e) {
        float2 cv = *(const float2*)&cs[e][2 * m];
#pragma unroll
        for (int oi = 0; oi < 4; ++oi) {
            int o = og * 4 + oi;
            float wr = fwr[(((size_t)hh * 16 + e) * 16 + o) * 64 + m];
            float wi = fwi[(((size_t)hh * 16 + e) * 16 + o) * 64 + m];
            dr[oi] += cv.x * wr - cv.y * wi;
            di[oi] += cv.x * wi + cv.y * wr;
        }
    }
#pragma unroll
    for (int oi = 0; oi < 4; ++oi) {
        int o = og * 4 + oi;
        float2 v = make_float2(dr[oi], di[oi]);
        *(float2*)&dd[((size_t)b * 128 + hh * 16 + o) * 128 + 2 * m] = v;
    }
}

// ---------------------------------------------------------------------------
// Inverse truncated DFT (fp32 compute, bf16 out in flat (B,H*E,L) order).
// ---------------------------------------------------------------------------
__global__ __launch_bounds__(256) void k_idft(const float* __restrict__ dd,
                                              const float* __restrict__ G,
                                              __bf16* __restrict__ y) {
    __shared__ float ds[128][65];
    const int b = blockIdx.y, t0 = blockIdx.x * 64;
    const int hog = threadIdx.x & 31, tg = threadIdx.x >> 5;
    const int tb = tg * 8;
    float4 acc4[8];
#pragma unroll
    for (int t = 0; t < 8; ++t) acc4[t] = f4_zero();
    for (int half = 0; half < 2; ++half) {
        if (half) __syncthreads();
        for (int idx = threadIdx.x; idx < 128 * 16; idx += 256) {
            int ho = idx >> 4, c4 = idx & 15;
            float4 v = f4_load(&dd[((size_t)b * 128 + ho) * 128 + half * 64 + c4 * 4]);
            ds[ho][c4 * 4 + 0] = v.x; ds[ho][c4 * 4 + 1] = v.y;
            ds[ho][c4 * 4 + 2] = v.z; ds[ho][c4 * 4 + 3] = v.w;
        }
        __syncthreads();
        for (int m2l = 0; m2l < 64; ++m2l) {
            int m2 = half * 64 + m2l;
            float4 dvec = make_float4(ds[hog][m2l], ds[hog + 32][m2l],
                                      ds[hog + 64][m2l], ds[hog + 96][m2l]);
            float4 g0 = f4_load(&G[(size_t)m2 * 512 + t0 + tb]);
            float4 g1 = f4_load(&G[(size_t)m2 * 512 + t0 + tb + 4]);
            f4_fma(acc4[0], g0.x, dvec); f4_fma(acc4[1], g0.y, dvec);
            f4_fma(acc4[2], g0.z, dvec); f4_fma(acc4[3], g0.w, dvec);
            f4_fma(acc4[4], g1.x, dvec); f4_fma(acc4[5], g1.y, dvec);
            f4_fma(acc4[6], g1.z, dvec); f4_fma(acc4[7], g1.w, dvec);
        }
    }
#pragma unroll
    for (int hj = 0; hj < 4; ++hj) {
        __bf16 tmp[8];
#pragma unroll
        for (int ti = 0; ti < 8; ++ti) {
            float v = (hj == 0) ? acc4[ti].x : (hj == 1) ? acc4[ti].y
                    : (hj == 2) ? acc4[ti].z : acc4[ti].w;
            tmp[ti] = (__bf16)v;
        }
        *(uint4*)&y[((size_t)b * 128 + hog + hj * 32) * 512 + t0 + tb] = *(uint4*)tmp;
    }
}

// ---------------------------------------------------------------------------
// Series decomp: out = x - movmean(x,25); writes fp32 + bf16 shadow.
// ---------------------------------------------------------------------------
__global__ __launch_bounds__(256) void k_decomp(const float* __restrict__ X,
                                                float* __restrict__ out,
                                                __bf16* __restrict__ outb) {
    __shared__ float xs[88][128];
    const int b = blockIdx.y, l0 = blockIdx.x * 64;
    for (int idx = threadIdx.x; idx < 88 * 32; idx += 256) {
        int r = idx >> 5, c4 = idx & 31;
        int gl = l0 - 12 + r;
        gl = gl < 0 ? 0 : (gl > 511 ? 511 : gl);
        f4_store(&xs[r][c4 * 4], f4_load(&X[((size_t)b * 512 + gl) * 128 + c4 * 4]));
    }
    __syncthreads();
    const int dg = threadIdx.x & 31, lg = threadIdx.x >> 5;
    const int d0 = dg * 4, base = lg * 8;
    float4 s = f4_zero();
#pragma unroll
    for (int w = 0; w < 25; ++w) {
        float4 v = f4_load(&xs[base + w][d0]);
        s.x += v.x; s.y += v.y; s.z += v.z; s.w += v.w;
    }
    const float inv = 1.0f / 25.0f;
#pragma unroll
    for (int i = 0; i < 8; ++i) {
        int t = base + 12 + i;
        float4 x = f4_load(&xs[t][d0]);
        float4 o = make_float4(x.x - s.x * inv, x.y - s.y * inv,
                               x.z - s.z * inv, x.w - s.w * inv);
        size_t gi = ((size_t)b * 512 + l0 + lg * 8 + i) * 128 + d0;
        f4_store(&out[gi], o);
        store_bf4(&outb[gi], o);
        if (i < 7) {
            float4 a = f4_load(&xs[base + 25 + i][d0]);
            float4 r = f4_load(&xs[base + i][d0]);
            s.x += a.x - r.x; s.y += a.y - r.y; s.z += a.z - r.z; s.w += a.w - r.w;
        }
    }
}

// ---------------------------------------------------------------------------
// LayerNorm over D=128; one wave per row.
// ---------------------------------------------------------------------------
__global__ __launch_bounds__(256) void k_ln(const float* __restrict__ X,
                                            const float* __restrict__ g,
                                            const float* __restrict__ bb,
                                            float* __restrict__ out) {
    const int row = blockIdx.x * 4 + (threadIdx.x >> 6);
    const int lane = threadIdx.x & 63;
    float2 v = *(const float2*)&X[(size_t)row * 128 + lane * 2];
    float s = v.x + v.y, ss = v.x * v.x + v.y * v.y;
#pragma unroll
    for (int o = 32; o; o >>= 1) {
        s += __shfl_xor(s, o);
        ss += __shfl_xor(ss, o);
    }
    float mu = s * (1.0f / 128.0f);
    float var = ss * (1.0f / 128.0f) - mu * mu;
    float rstd = rsqrtf(var + 1e-5f);
    float2 gg = *(const float2*)&g[lane * 2];
    float2 bv = *(const float2*)&bb[lane * 2];
    float2 o;
    o.x = (v.x - mu) * rstd * gg.x + bv.x;
    o.y = (v.y - mu) * rstd * gg.y + bv.y;
    *(float2*)&out[(size_t)row * 128 + lane * 2] = o;
}

__global__ __launch_bounds__(128) void k_colmean(const float* __restrict__ X,
                                                 float* __restrict__ cm) {
    const int b = blockIdx.y, l0 = blockIdx.x * 64, d = threadIdx.x;
    float s = 0.f;
    for (int l = l0; l < l0 + 64; ++l) s += X[((size_t)b * 512 + l) * 128 + d];
    atomicAdd(&cm[b * 128 + d], s);
}

__global__ __launch_bounds__(128) void k_final(const float* __restrict__ hn,
                                               const float* __restrict__ cm,
                                               const float* __restrict__ mark,
                                               const float* __restrict__ pw,
                                               const float* __restrict__ pb,
                                               float* __restrict__ out) {
    const int b = blockIdx.y, l0 = blockIdx.x * 128, d = threadIdx.x;
    const float c = cm[b * 128 + d] * (1.0f / 512.0f);
    float acc = 0.f;
    for (int l = l0; l < l0 + 128; ++l) {
        float v = hn[((size_t)b * 512 + l) * 128 + d] - c;
        acc += gelu_f(v) * mark[((size_t)b * 128 + d) * 512 + l] * pw[l * 128 + d];
    }
    __shared__ float red[2];
#pragma unroll
    for (int o = 32; o; o >>= 1) acc += __shfl_xor(acc, o);
    if ((threadIdx.x & 63) == 0) red[threadIdx.x >> 6] = acc;
    __syncthreads();
    if (threadIdx.x == 0) {
        float tot = red[0] + red[1];
        if (blockIdx.x == 0) tot += pb[0];
        atomicAdd(&out[b], tot);
    }
}

// ---------------------------------------------------------------------------
extern "C" void kernel_launch(void* const* d_in, const int* in_sizes, int n_in,
                              void* d_out, int out_size, void* d_ws, size_t ws_size,
                              hipStream_t stream) {
    const float* xe   = (const float*)d_in[0];
    const float* mark = (const float*)d_in[1];
    const float* cw   = (const float*)d_in[4];
    const float* Wq   = (const float*)d_in[5];
    const float* bq   = (const float*)d_in[6];
    const float* Wo   = (const float*)d_in[7];
    const float* bo   = (const float*)d_in[8];
    const float* fwr  = (const float*)d_in[9];
    const float* fwi  = (const float*)d_in[10];
    const float* W1   = (const float*)d_in[11];
    const float* W2   = (const float*)d_in[12];
    const float* lng  = (const float*)d_in[13];
    const float* lnb  = (const float*)d_in[14];
    const float* pw   = (const float*)d_in[15];
    const float* pb   = (const float*)d_in[16];
    float* out = (float*)d_out;

    // Workspace layout (floats). Total 25,477,120 floats = 101.9 MB.
    float* ws   = (float*)d_ws;
    float* Ftt  = ws;                        // 65536
    float* G    = ws + 65536;                // 65536
    float* h    = ws + 131072;               // 8388608 fp32 state
    float* bufA = ws + 8519680;              // 8388608 (q / dd / s / ffn-out / hn)
    __bf16* hb  = (__bf16*)(ws + 16908288);  // 8388608 bf16
    float* yrg  = ws + 21102592;             // 4194304 (pe | cbuf | yb overlay)
    float* cm   = ws + 25296896;             // 16384
    __bf16* wbf = (__bf16*)(ws + 25313280);  // 327680 bf16
    float* pe   = yrg;
    float* cbuf = yrg;
    __bf16* yb  = (__bf16*)yrg;
    __bf16* Wqt = wbf;
    __bf16* Wot = wbf + 32768;
    __bf16* W1t = wbf + 65536;
    __bf16* W2t = wbf + 196608;

    k_init<<<256, 256, 0, stream>>>(pe, Ftt, G);
    k_castw<<<1280, 256, 0, stream>>>(Wq, Wo, W1, W2, wbf);
    k_embed<<<dim3(8, 128), 256, 0, stream>>>(xe, cw, pe, h, hb);
    for (int l = 0; l < NLAYER; ++l) {
        // q = hb @ Wq + bq   (fp32 out into bufA)
        k_mgemm<false><<<512, 256, 0, stream>>>(hb, Wqt + l * 16384, bq + l * 128,
                                                nullptr, bufA);
        k_fdft<<<dim3(4, 128), 256, 0, stream>>>(bufA, Ftt, cbuf);
        // dd overwrites q region (q dead after fdft)
        k_mix<<<dim3(8, 128), 256, 0, stream>>>(cbuf, fwr + l * 131072,
                                                fwi + l * 131072, bufA);
        // yb overwrites cbuf region (cbuf dead after mix)
        k_idft<<<dim3(8, 128), 256, 0, stream>>>(bufA, G, yb);
        // s = yb @ Wo + bo + h  (dd dead)
        k_mgemm<true><<<512, 256, 0, stream>>>(yb, Wot + l * 16384, bo + l * 128,
                                               h, bufA);
        k_decomp<<<dim3(8, 128), 256, 0, stream>>>(bufA, h, hb);
        k_ffnm<<<512, 256, 0, stream>>>(hb, h, W1t + l * 65536, W2t + l * 65536, bufA);
        k_decomp<<<dim3(8, 128), 256, 0, stream>>>(bufA, h, hb);
    }
    k_ln<<<16384, 256, 0, stream>>>(h, lng, lnb, bufA);
    hipMemsetAsync(cm, 0, 16384 * sizeof(float), stream);
    k_colmean<<<dim3(8, 128), 128, 0, stream>>>(bufA, cm);
    hipMemsetAsync(d_out, 0, 128 * sizeof(float), stream);
    k_final<<<dim3(4, 128), 128, 0, stream>>>(bufA, cm, mark, pw, pb, out);

    (void)in_sizes; (void)n_in; (void)out_size; (void)ws_size;
}

// Round 3
// 742.066 us; speedup vs baseline: 1.8321x; 1.2717x over previous
//
#include <hip/hip_runtime.h>
#include <math.h>

#define DFF 512
#define NLAYER 2

typedef __bf16 bf16x8 __attribute__((ext_vector_type(8)));
typedef float f32x4 __attribute__((ext_vector_type(4)));

__device__ __forceinline__ float4 f4_load(const float* p) { return *(const float4*)p; }
__device__ __forceinline__ void f4_store(float* p, float4 v) { *(float4*)p = v; }
__device__ __forceinline__ float4 f4_zero() { return make_float4(0.f, 0.f, 0.f, 0.f); }
__device__ __forceinline__ void f4_fma(float4& a, float s, const float4 w) {
    a.x += s * w.x; a.y += s * w.y; a.z += s * w.z; a.w += s * w.w;
}
__device__ __forceinline__ float gelu_f(float x) {
    return 0.5f * x * (1.0f + erff(x * 0.70710678118654752440f));
}
// XOR-swizzled LDS offset for a 128-elem bf16 row (16B-group swizzle, no pad).
__device__ __forceinline__ int sw_off(int r, int c) {
    return (r << 7) + (((c >> 3) ^ (r & 7)) << 3) + (c & 7);
}
__device__ __forceinline__ void store_bf4(__bf16* p, float4 v) {
    __bf16 t[4] = {(__bf16)v.x, (__bf16)v.y, (__bf16)v.z, (__bf16)v.w};
    *(uint2*)p = *(uint2*)t;
}

// ---------------------------------------------------------------------------
// Init: positional encoding, forward DFT table Ftt[128][512], inverse G.
// ---------------------------------------------------------------------------
__global__ __launch_bounds__(256) void k_init(float* __restrict__ pe,
                                              float* __restrict__ Ftt,
                                              float* __restrict__ G) {
    int idx = blockIdx.x * 256 + threadIdx.x;   // 0..65535
    {
        int l = idx >> 7, d = idx & 127;
        int j = d >> 1;
        double div = exp((double)(2 * j) * (-log(10000.0) / 128.0));
        double a = (double)l * div;
        pe[idx] = (d & 1) ? (float)cos(a) : (float)sin(a);
    }
    {
        int m2 = idx >> 9, t = idx & 511;
        int m = m2 >> 1;
        int r = (m * t) & 511;
        double ang = (double)r * (6.283185307179586476925287 / 512.0);
        float cv = (float)cos(ang), sv = (float)sin(ang);
        float f = (m2 & 1) ? -sv : cv;
        Ftt[idx] = f;
        float s = (m == 0) ? (1.0f / 512.0f) : (2.0f / 512.0f);
        G[idx] = f * s;
    }
}

// ---------------------------------------------------------------------------
// Cast+transpose weights to bf16: Wqt/Wot (n-major), W1t[f][k], W2t[n][f],
// plus conv weights cwtk[s][d][i] (n-major per shift).
// ---------------------------------------------------------------------------
__global__ __launch_bounds__(256) void k_castw(const float* __restrict__ Wq,
                                               const float* __restrict__ Wo,
                                               const float* __restrict__ W1,
                                               const float* __restrict__ W2,
                                               const float* __restrict__ cw,
                                               __bf16* __restrict__ wbf,
                                               __bf16* __restrict__ cwtk) {
    int i = blockIdx.x * 256 + threadIdx.x;   // < 376832
    if (i < 65536) {
        int r = i & 16383, l = (i >> 14) & 1;
        int n = r >> 7, k = r & 127;
        const float* W = (i >= 32768) ? Wo : Wq;
        wbf[i] = (__bf16)W[l * 16384 + k * 128 + n];
    } else if (i < 196608) {
        int j = i - 65536;
        int l = j >> 16, r = j & 65535;
        int f = r >> 7, k = r & 127;
        wbf[i] = (__bf16)W1[l * 65536 + k * 512 + f];
    } else if (i < 327680) {
        int j = i - 196608;
        int l = j >> 16, r = j & 65535;
        int n = r >> 9, f = r & 511;
        wbf[i] = (__bf16)W2[l * 65536 + f * 128 + n];
    } else if (i < 376832) {
        int j = i - 327680;          // s*16384 + d*128 + ii
        int s = j >> 14, r = j & 16383;
        int d = r >> 7, ii = r & 127;
        cwtk[j] = (__bf16)cw[(d * 128 + ii) * 3 + s];
    }
}

// ---------------------------------------------------------------------------
// Transpose x_enc (B,D,L) fp32 -> xt (B,L,D) bf16.
// ---------------------------------------------------------------------------
__global__ __launch_bounds__(256) void k_xpose(const float* __restrict__ xe,
                                               __bf16* __restrict__ xt) {
    __shared__ float ts[128][65];
    const int b = blockIdx.y, l0 = blockIdx.x * 64;
    for (int idx = threadIdx.x; idx < 128 * 16; idx += 256) {
        int d = idx >> 4, c4 = idx & 15;
        float4 v = f4_load(&xe[((size_t)b * 128 + d) * 512 + l0 + c4 * 4]);
        ts[d][c4 * 4 + 0] = v.x; ts[d][c4 * 4 + 1] = v.y;
        ts[d][c4 * 4 + 2] = v.z; ts[d][c4 * 4 + 3] = v.w;
    }
    __syncthreads();
#pragma unroll
    for (int p = 0; p < 4; ++p) {
        int l = (threadIdx.x >> 4) + p * 16;
        int d0 = (threadIdx.x & 15) * 8;
        __bf16 tmp[8];
#pragma unroll
        for (int j = 0; j < 8; ++j) tmp[j] = (__bf16)ts[d0 + j][l];
        *(uint4*)&xt[((size_t)b * 512 + l0 + l) * 128 + d0] = *(uint4*)tmp;
    }
}

// ---------------------------------------------------------------------------
// MFMA embed: h[b,l,d] = sum_s sum_i xt[b,(l-1+s)%512,i]*cwtk[s][d][i] + pe.
// Block = 128 output rows (one (b, l-tile)); stages 130 rows w/ circular halo.
// ---------------------------------------------------------------------------
__global__ __launch_bounds__(256) void k_embed_m(const __bf16* __restrict__ xt,
                                                 const __bf16* __restrict__ cwtk,
                                                 const float* __restrict__ pe,
                                                 float* __restrict__ h,
                                                 __bf16* __restrict__ hb) {
    __shared__ __align__(16) __bf16 xs[130 * 128];
    const int b = blockIdx.x >> 2, l0 = (blockIdx.x & 3) * 128;
    for (int c = threadIdx.x; c < 130 * 16; c += 256) {
        int r = c >> 4, g = c & 15;
        int gl = (l0 - 1 + r) & 511;
        *(uint4*)&xs[(r << 7) + ((g ^ (r & 7)) << 3)] =
            *(const uint4*)&xt[(((size_t)b * 512 + gl) << 7) + (g << 3)];
    }
    __syncthreads();
    const int lane = threadIdx.x & 63, wid = threadIdx.x >> 6;
    const int wrow = (wid & 1) * 64, wcol = (wid >> 1) * 64;
    const int m16 = lane & 15, quad = lane >> 4;
    f32x4 acc[4][4];
#pragma unroll
    for (int a = 0; a < 4; ++a)
#pragma unroll
        for (int bb = 0; bb < 4; ++bb) acc[a][bb] = {0.f, 0.f, 0.f, 0.f};
#pragma unroll
    for (int s = 0; s < 3; ++s) {
#pragma unroll
        for (int ks = 0; ks < 4; ++ks) {
            const int ko = ks * 32 + quad * 8;
            bf16x8 af[4], bfr[4];
#pragma unroll
            for (int rt = 0; rt < 4; ++rt) {
                int r = wrow + rt * 16 + m16 + s;
                af[rt] = *(const bf16x8*)&xs[(r << 7) + (((ks * 4 + quad) ^ (r & 7)) << 3)];
            }
#pragma unroll
            for (int ct = 0; ct < 4; ++ct)
                bfr[ct] = *(const bf16x8*)&cwtk[((size_t)(s * 128 + wcol + ct * 16 + m16) << 7) + ko];
#pragma unroll
            for (int rt = 0; rt < 4; ++rt)
#pragma unroll
                for (int ct = 0; ct < 4; ++ct)
                    acc[rt][ct] = __builtin_amdgcn_mfma_f32_16x16x32_bf16(
                        af[rt], bfr[ct], acc[rt][ct], 0, 0, 0);
        }
    }
#pragma unroll
    for (int ct = 0; ct < 4; ++ct) {
        int gcol = wcol + ct * 16 + m16;
#pragma unroll
        for (int rt = 0; rt < 4; ++rt)
#pragma unroll
            for (int r = 0; r < 4; ++r) {
                int l = l0 + wrow + rt * 16 + quad * 4 + r;
                float v = acc[rt][ct][r] + pe[l * 128 + gcol];
                size_t gi = (((size_t)b * 512 + l) << 7) + gcol;
                h[gi] = v;
                hb[gi] = (__bf16)v;
            }
    }
}

// ---------------------------------------------------------------------------
// MFMA GEMM: out(M x 128 fp32) = Xb(M x 128 bf16) @ W(128x128) + bias (+R).
// ---------------------------------------------------------------------------
template <bool RES>
__global__ __launch_bounds__(256) void k_mgemm(const __bf16* __restrict__ Xb,
                                               const __bf16* __restrict__ Wt,
                                               const float* __restrict__ bias,
                                               const float* __restrict__ R,
                                               float* __restrict__ out) {
    __shared__ __align__(16) __bf16 xs[128 * 128];
    const int rowBase = blockIdx.x * 128;
#pragma unroll
    for (int i = 0; i < 8; ++i) {
        int c = i * 256 + threadIdx.x;
        int r = c >> 4, g = c & 15;
        *(uint4*)&xs[(r << 7) + ((g ^ (r & 7)) << 3)] =
            *(const uint4*)&Xb[(((size_t)rowBase + r) << 7) + (g << 3)];
    }
    __syncthreads();
    const int lane = threadIdx.x & 63, wid = threadIdx.x >> 6;
    const int wrow = (wid & 1) * 64, wcol = (wid >> 1) * 64;
    const int m16 = lane & 15, quad = lane >> 4;
    f32x4 acc[4][4];
#pragma unroll
    for (int a = 0; a < 4; ++a)
#pragma unroll
        for (int b = 0; b < 4; ++b) acc[a][b] = {0.f, 0.f, 0.f, 0.f};
#pragma unroll
    for (int ks = 0; ks < 4; ++ks) {
        const int ko = ks * 32 + quad * 8;
        const int xg = (((ks * 4 + quad) ^ (m16 & 7)) << 3);
        bf16x8 af[4], bfr[4];
#pragma unroll
        for (int rt = 0; rt < 4; ++rt)
            af[rt] = *(const bf16x8*)&xs[((wrow + rt * 16 + m16) << 7) + xg];
#pragma unroll
        for (int ct = 0; ct < 4; ++ct)
            bfr[ct] = *(const bf16x8*)&Wt[((size_t)(wcol + ct * 16 + m16) << 7) + ko];
#pragma unroll
        for (int rt = 0; rt < 4; ++rt)
#pragma unroll
            for (int ct = 0; ct < 4; ++ct)
                acc[rt][ct] = __builtin_amdgcn_mfma_f32_16x16x32_bf16(
                    af[rt], bfr[ct], acc[rt][ct], 0, 0, 0);
    }
#pragma unroll
    for (int ct = 0; ct < 4; ++ct) {
        int gcol = wcol + ct * 16 + m16;
        float bv = bias[gcol];
#pragma unroll
        for (int rt = 0; rt < 4; ++rt)
#pragma unroll
            for (int r = 0; r < 4; ++r) {
                size_t gi = ((size_t)(rowBase + wrow + rt * 16 + quad * 4 + r) << 7) + gcol;
                float v = acc[rt][ct][r] + bv;
                if (RES) v += R[gi];
                out[gi] = v;
            }
    }
}

// ---------------------------------------------------------------------------
// MFMA FFN: out = Xf + gelu(X @ W1) @ W2. Chunks of 128 over DFF through LDS.
// ---------------------------------------------------------------------------
__global__ __launch_bounds__(256) void k_ffnm(const __bf16* __restrict__ Xb,
                                              const float* __restrict__ Xf,
                                              const __bf16* __restrict__ W1t,
                                              const __bf16* __restrict__ W2t,
                                              float* __restrict__ out) {
    __shared__ __align__(16) __bf16 xs[128 * 128];
    __shared__ __align__(16) __bf16 ts[128 * 128];
    const int rowBase = blockIdx.x * 128;
#pragma unroll
    for (int i = 0; i < 8; ++i) {
        int c = i * 256 + threadIdx.x;
        int r = c >> 4, g = c & 15;
        *(uint4*)&xs[(r << 7) + ((g ^ (r & 7)) << 3)] =
            *(const uint4*)&Xb[(((size_t)rowBase + r) << 7) + (g << 3)];
    }
    __syncthreads();
    const int lane = threadIdx.x & 63, wid = threadIdx.x >> 6;
    const int wrow = (wid & 1) * 64, wcol = (wid >> 1) * 64;
    const int m16 = lane & 15, quad = lane >> 4;
    f32x4 acc2[4][4];
#pragma unroll
    for (int a = 0; a < 4; ++a)
#pragma unroll
        for (int b = 0; b < 4; ++b) acc2[a][b] = {0.f, 0.f, 0.f, 0.f};

    for (int f0 = 0; f0 < DFF; f0 += 128) {
        f32x4 c1[4][4];
#pragma unroll
        for (int a = 0; a < 4; ++a)
#pragma unroll
            for (int b = 0; b < 4; ++b) c1[a][b] = {0.f, 0.f, 0.f, 0.f};
#pragma unroll
        for (int ks = 0; ks < 4; ++ks) {
            const int ko = ks * 32 + quad * 8;
            const int xg = (((ks * 4 + quad) ^ (m16 & 7)) << 3);
            bf16x8 af[4], bfr[4];
#pragma unroll
            for (int rt = 0; rt < 4; ++rt)
                af[rt] = *(const bf16x8*)&xs[((wrow + rt * 16 + m16) << 7) + xg];
#pragma unroll
            for (int ct = 0; ct < 4; ++ct)
                bfr[ct] = *(const bf16x8*)&W1t[((size_t)(f0 + wcol + ct * 16 + m16) << 7) + ko];
#pragma unroll
            for (int rt = 0; rt < 4; ++rt)
#pragma unroll
                for (int ct = 0; ct < 4; ++ct)
                    c1[rt][ct] = __builtin_amdgcn_mfma_f32_16x16x32_bf16(
                        af[rt], bfr[ct], c1[rt][ct], 0, 0, 0);
        }
#pragma unroll
        for (int rt = 0; rt < 4; ++rt)
#pragma unroll
            for (int ct = 0; ct < 4; ++ct)
#pragma unroll
                for (int r = 0; r < 4; ++r) {
                    int lrow = wrow + rt * 16 + quad * 4 + r;
                    int lcol = wcol + ct * 16 + m16;
                    ts[sw_off(lrow, lcol)] = (__bf16)gelu_f(c1[rt][ct][r]);
                }
        __syncthreads();
#pragma unroll
        for (int ks = 0; ks < 4; ++ks) {
            const int ko = ks * 32 + quad * 8;
            const int xg = (((ks * 4 + quad) ^ (m16 & 7)) << 3);
            bf16x8 af[4], bfr[4];
#pragma unroll
            for (int rt = 0; rt < 4; ++rt)
                af[rt] = *(const bf16x8*)&ts[((wrow + rt * 16 + m16) << 7) + xg];
#pragma unroll
            for (int ct = 0; ct < 4; ++ct)
                bfr[ct] = *(const bf16x8*)&W2t[((size_t)(wcol + ct * 16 + m16) << 9) + f0 + ko];
#pragma unroll
            for (int rt = 0; rt < 4; ++rt)
#pragma unroll
                for (int ct = 0; ct < 4; ++ct)
                    acc2[rt][ct] = __builtin_amdgcn_mfma_f32_16x16x32_bf16(
                        af[rt], bfr[ct], acc2[rt][ct], 0, 0, 0);
        }
        __syncthreads();
    }
#pragma unroll
    for (int ct = 0; ct < 4; ++ct) {
        int gcol = wcol + ct * 16 + m16;
#pragma unroll
        for (int rt = 0; rt < 4; ++rt)
#pragma unroll
            for (int r = 0; r < 4; ++r) {
                size_t gi = ((size_t)(rowBase + wrow + rt * 16 + quad * 4 + r) << 7) + gcol;
                out[gi] = acc2[rt][ct][r] + Xf[gi];
            }
    }
}

// ---------------------------------------------------------------------------
// Forward truncated DFT (fp32): c[b,d,m2] = sum_t q[b,t,d] * Ftt[m2][t]
// ---------------------------------------------------------------------------
__global__ __launch_bounds__(256) void k_fdft(const float* __restrict__ q,
                                              const float* __restrict__ Ftt,
                                              float* __restrict__ cbuf) {
    __shared__ float fs[32][512];
    const int b = blockIdx.y, m2b = blockIdx.x * 32;
    for (int idx = threadIdx.x; idx < 32 * 128; idx += 256) {
        int r = idx >> 7, c4 = idx & 127;
        f4_store(&fs[r][c4 * 4], f4_load(&Ftt[(m2b + r) * 512 + c4 * 4]));
    }
    __syncthreads();
    const int dg = threadIdx.x & 31, mg = threadIdx.x >> 5;
    const int d0 = dg * 4, m0 = mg * 4;
    float4 acc4[4];
#pragma unroll
    for (int m = 0; m < 4; ++m) acc4[m] = f4_zero();
    for (int t = 0; t < 512; t += 4) {
        float4 q0 = f4_load(&q[((size_t)b * 512 + t + 0) * 128 + d0]);
        float4 q1 = f4_load(&q[((size_t)b * 512 + t + 1) * 128 + d0]);
        float4 q2 = f4_load(&q[((size_t)b * 512 + t + 2) * 128 + d0]);
        float4 q3 = f4_load(&q[((size_t)b * 512 + t + 3) * 128 + d0]);
#pragma unroll
        for (int mj = 0; mj < 4; ++mj) {
            float4 f = f4_load(&fs[m0 + mj][t]);
            f4_fma(acc4[mj], f.x, q0); f4_fma(acc4[mj], f.y, q1);
            f4_fma(acc4[mj], f.z, q2); f4_fma(acc4[mj], f.w, q3);
        }
    }
    f4_store(&cbuf[((size_t)b * 128 + d0 + 0) * 128 + m2b + m0],
             make_float4(acc4[0].x, acc4[1].x, acc4[2].x, acc4[3].x));
    f4_store(&cbuf[((size_t)b * 128 + d0 + 1) * 128 + m2b + m0],
             make_float4(acc4[0].y, acc4[1].y, acc4[2].y, acc4[3].y));
    f4_store(&cbuf[((size_t)b * 128 + d0 + 2) * 128 + m2b + m0],
             make_float4(acc4[0].z, acc4[1].z, acc4[2].z, acc4[3].z));
    f4_store(&cbuf[((size_t)b * 128 + d0 + 3) * 128 + m2b + m0],
             make_float4(acc4[0].w, acc4[1].w, acc4[2].w, acc4[3].w));
}

// ---------------------------------------------------------------------------
// Mode mix (fp32, tiny): complex 16-vec x 16x16 per (b,h,m).
// ---------------------------------------------------------------------------
__global__ __launch_bounds__(256) void k_mix(const float* __restrict__ cbuf,
                                             const float* __restrict__ fwr,
                                             const float* __restrict__ fwi,
                                             float* __restrict__ dd) {
    __shared__ float cs[16][128];
    const int hh = blockIdx.x, b = blockIdx.y;
    for (int idx = threadIdx.x; idx < 16 * 32; idx += 256) {
        int e = idx >> 5, c4 = idx & 31;
        f4_store(&cs[e][c4 * 4],
                 f4_load(&cbuf[((size_t)b * 128 + hh * 16 + e) * 128 + c4 * 4]));
    }
    __syncthreads();
    const int m = threadIdx.x & 63, og = threadIdx.x >> 6;
    float dr[4] = {0.f, 0.f, 0.f, 0.f}, di[4] = {0.f, 0.f, 0.f, 0.f};
    for (int e = 0; e < 16; ++e) {
        float2 cv = *(const float2*)&cs[e][2 * m];
#pragma unroll
        for (int oi = 0; oi < 4; ++oi) {
            int o = og * 4 + oi;
            float wr = fwr[(((size_t)hh * 16 + e) * 16 + o) * 64 + m];
            float wi = fwi[(((size_t)hh * 16 + e) * 16 + o) * 64 + m];
            dr[oi] += cv.x * wr - cv.y * wi;
            di[oi] += cv.x * wi + cv.y * wr;
        }
    }
#pragma unroll
    for (int oi = 0; oi < 4; ++oi) {
        int o = og * 4 + oi;
        float2 v = make_float2(dr[oi], di[oi]);
        *(float2*)&dd[((size_t)b * 128 + hh * 16 + o) * 128 + 2 * m] = v;
    }
}

// ---------------------------------------------------------------------------
// Inverse truncated DFT (fp32 compute, bf16 out in flat (B,H*E,L) order).
// ---------------------------------------------------------------------------
__global__ __launch_bounds__(256) void k_idft(const float* __restrict__ dd,
                                              const float* __restrict__ G,
                                              __bf16* __restrict__ y) {
    __shared__ float ds[128][65];
    const int b = blockIdx.y, t0 = blockIdx.x * 64;
    const int hog = threadIdx.x & 31, tg = threadIdx.x >> 5;
    const int tb = tg * 8;
    float4 acc4[8];
#pragma unroll
    for (int t = 0; t < 8; ++t) acc4[t] = f4_zero();
    for (int half = 0; half < 2; ++half) {
        if (half) __syncthreads();
        for (int idx = threadIdx.x; idx < 128 * 16; idx += 256) {
            int ho = idx >> 4, c4 = idx & 15;
            float4 v = f4_load(&dd[((size_t)b * 128 + ho) * 128 + half * 64 + c4 * 4]);
            ds[ho][c4 * 4 + 0] = v.x; ds[ho][c4 * 4 + 1] = v.y;
            ds[ho][c4 * 4 + 2] = v.z; ds[ho][c4 * 4 + 3] = v.w;
        }
        __syncthreads();
        for (int m2l = 0; m2l < 64; ++m2l) {
            int m2 = half * 64 + m2l;
            float4 dvec = make_float4(ds[hog][m2l], ds[hog + 32][m2l],
                                      ds[hog + 64][m2l], ds[hog + 96][m2l]);
            float4 g0 = f4_load(&G[(size_t)m2 * 512 + t0 + tb]);
            float4 g1 = f4_load(&G[(size_t)m2 * 512 + t0 + tb + 4]);
            f4_fma(acc4[0], g0.x, dvec); f4_fma(acc4[1], g0.y, dvec);
            f4_fma(acc4[2], g0.z, dvec); f4_fma(acc4[3], g0.w, dvec);
            f4_fma(acc4[4], g1.x, dvec); f4_fma(acc4[5], g1.y, dvec);
            f4_fma(acc4[6], g1.z, dvec); f4_fma(acc4[7], g1.w, dvec);
        }
    }
#pragma unroll
    for (int hj = 0; hj < 4; ++hj) {
        __bf16 tmp[8];
#pragma unroll
        for (int ti = 0; ti < 8; ++ti) {
            float v = (hj == 0) ? acc4[ti].x : (hj == 1) ? acc4[ti].y
                    : (hj == 2) ? acc4[ti].z : acc4[ti].w;
            tmp[ti] = (__bf16)v;
        }
        *(uint4*)&y[((size_t)b * 128 + hog + hj * 32) * 512 + t0 + tb] = *(uint4*)tmp;
    }
}

// ---------------------------------------------------------------------------
// Series decomp: out = x - movmean(x,25); writes fp32 + bf16 shadow.
// ---------------------------------------------------------------------------
__global__ __launch_bounds__(256) void k_decomp(const float* __restrict__ X,
                                                float* __restrict__ out,
                                                __bf16* __restrict__ outb) {
    __shared__ float xs[88][128];
    const int b = blockIdx.y, l0 = blockIdx.x * 64;
    for (int idx = threadIdx.x; idx < 88 * 32; idx += 256) {
        int r = idx >> 5, c4 = idx & 31;
        int gl = l0 - 12 + r;
        gl = gl < 0 ? 0 : (gl > 511 ? 511 : gl);
        f4_store(&xs[r][c4 * 4], f4_load(&X[((size_t)b * 512 + gl) * 128 + c4 * 4]));
    }
    __syncthreads();
    const int dg = threadIdx.x & 31, lg = threadIdx.x >> 5;
    const int d0 = dg * 4, base = lg * 8;
    float4 s = f4_zero();
#pragma unroll
    for (int w = 0; w < 25; ++w) {
        float4 v = f4_load(&xs[base + w][d0]);
        s.x += v.x; s.y += v.y; s.z += v.z; s.w += v.w;
    }
    const float inv = 1.0f / 25.0f;
#pragma unroll
    for (int i = 0; i < 8; ++i) {
        int t = base + 12 + i;
        float4 x = f4_load(&xs[t][d0]);
        float4 o = make_float4(x.x - s.x * inv, x.y - s.y * inv,
                               x.z - s.z * inv, x.w - s.w * inv);
        size_t gi = ((size_t)b * 512 + l0 + lg * 8 + i) * 128 + d0;
        f4_store(&out[gi], o);
        store_bf4(&outb[gi], o);
        if (i < 7) {
            float4 a = f4_load(&xs[base + 25 + i][d0]);
            float4 r = f4_load(&xs[base + i][d0]);
            s.x += a.x - r.x; s.y += a.y - r.y; s.z += a.z - r.z; s.w += a.w - r.w;
        }
    }
}

// ---------------------------------------------------------------------------
// LayerNorm over D=128; one wave per row.
// ---------------------------------------------------------------------------
__global__ __launch_bounds__(256) void k_ln(const float* __restrict__ X,
                                            const float* __restrict__ g,
                                            const float* __restrict__ bb,
                                            float* __restrict__ out) {
    const int row = blockIdx.x * 4 + (threadIdx.x >> 6);
    const int lane = threadIdx.x & 63;
    float2 v = *(const float2*)&X[(size_t)row * 128 + lane * 2];
    float s = v.x + v.y, ss = v.x * v.x + v.y * v.y;
#pragma unroll
    for (int o = 32; o; o >>= 1) {
        s += __shfl_xor(s, o);
        ss += __shfl_xor(ss, o);
    }
    float mu = s * (1.0f / 128.0f);
    float var = ss * (1.0f / 128.0f) - mu * mu;
    float rstd = rsqrtf(var + 1e-5f);
    float2 gg = *(const float2*)&g[lane * 2];
    float2 bv = *(const float2*)&bb[lane * 2];
    float2 o;
    o.x = (v.x - mu) * rstd * gg.x + bv.x;
    o.y = (v.y - mu) * rstd * gg.y + bv.y;
    *(float2*)&out[(size_t)row * 128 + lane * 2] = o;
}

__global__ __launch_bounds__(128) void k_colmean(const float* __restrict__ X,
                                                 float* __restrict__ cm) {
    const int b = blockIdx.y, l0 = blockIdx.x * 64, d = threadIdx.x;
    float s = 0.f;
    for (int l = l0; l < l0 + 64; ++l) s += X[((size_t)b * 512 + l) * 128 + d];
    atomicAdd(&cm[b * 128 + d], s);
}

__global__ __launch_bounds__(128) void k_final(const float* __restrict__ hn,
                                               const float* __restrict__ cm,
                                               const float* __restrict__ mark,
                                               const float* __restrict__ pw,
                                               const float* __restrict__ pb,
                                               float* __restrict__ out) {
    const int b = blockIdx.y, l0 = blockIdx.x * 128, d = threadIdx.x;
    const float c = cm[b * 128 + d] * (1.0f / 512.0f);
    float acc = 0.f;
    for (int l = l0; l < l0 + 128; ++l) {
        float v = hn[((size_t)b * 512 + l) * 128 + d] - c;
        acc += gelu_f(v) * mark[((size_t)b * 128 + d) * 512 + l] * pw[l * 128 + d];
    }
    __shared__ float red[2];
#pragma unroll
    for (int o = 32; o; o >>= 1) acc += __shfl_xor(acc, o);
    if ((threadIdx.x & 63) == 0) red[threadIdx.x >> 6] = acc;
    __syncthreads();
    if (threadIdx.x == 0) {
        float tot = red[0] + red[1];
        if (blockIdx.x == 0) tot += pb[0];
        atomicAdd(&out[b], tot);
    }
}

// ---------------------------------------------------------------------------
extern "C" void kernel_launch(void* const* d_in, const int* in_sizes, int n_in,
                              void* d_out, int out_size, void* d_ws, size_t ws_size,
                              hipStream_t stream) {
    const float* xe   = (const float*)d_in[0];
    const float* mark = (const float*)d_in[1];
    const float* cw   = (const float*)d_in[4];
    const float* Wq   = (const float*)d_in[5];
    const float* bq   = (const float*)d_in[6];
    const float* Wo   = (const float*)d_in[7];
    const float* bo   = (const float*)d_in[8];
    const float* fwr  = (const float*)d_in[9];
    const float* fwi  = (const float*)d_in[10];
    const float* W1   = (const float*)d_in[11];
    const float* W2   = (const float*)d_in[12];
    const float* lng  = (const float*)d_in[13];
    const float* lnb  = (const float*)d_in[14];
    const float* pw   = (const float*)d_in[15];
    const float* pb   = (const float*)d_in[16];
    float* out = (float*)d_out;

    // Workspace layout (floats). Total 25,477,120 floats = 101.9 MB.
    float* ws   = (float*)d_ws;
    float* Ftt  = ws;                        // 65536
    float* G    = ws + 65536;                // 65536
    float* h    = ws + 131072;               // 8388608 fp32 state
    float* bufA = ws + 8519680;              // 8388608 (xt / q / dd / s / hn)
    __bf16* hb  = (__bf16*)(ws + 16908288);  // 8388608 bf16
    float* yrg  = ws + 21102592;             // 4194304 (pe+cwtk | cbuf | yb)
    float* cm   = ws + 25296896;             // 16384
    __bf16* wbf = (__bf16*)(ws + 25313280);  // 327680 bf16
    float* pe   = yrg;                       // [0, 65536) of yrg
    __bf16* cwtk = (__bf16*)(yrg + 65536);   // 49152 bf16 (dead after embed)
    float* cbuf = yrg;
    __bf16* yb  = (__bf16*)yrg;
    __bf16* xt  = (__bf16*)bufA;             // dead after embed
    __bf16* Wqt = wbf;
    __bf16* Wot = wbf + 32768;
    __bf16* W1t = wbf + 65536;
    __bf16* W2t = wbf + 196608;

    k_init<<<256, 256, 0, stream>>>(pe, Ftt, G);
    k_castw<<<1472, 256, 0, stream>>>(Wq, Wo, W1, W2, cw, wbf, cwtk);
    k_xpose<<<dim3(8, 128), 256, 0, stream>>>(xe, xt);
    k_embed_m<<<512, 256, 0, stream>>>(xt, cwtk, pe, h, hb);
    for (int l = 0; l < NLAYER; ++l) {
        k_mgemm<false><<<512, 256, 0, stream>>>(hb, Wqt + l * 16384, bq + l * 128,
                                                nullptr, bufA);
        k_fdft<<<dim3(4, 128), 256, 0, stream>>>(bufA, Ftt, cbuf);
        k_mix<<<dim3(8, 128), 256, 0, stream>>>(cbuf, fwr + l * 131072,
                                                fwi + l * 131072, bufA);
        k_idft<<<dim3(8, 128), 256, 0, stream>>>(bufA, G, yb);
        k_mgemm<true><<<512, 256, 0, stream>>>(yb, Wot + l * 16384, bo + l * 128,
                                               h, bufA);
        k_decomp<<<dim3(8, 128), 256, 0, stream>>>(bufA, h, hb);
        k_ffnm<<<512, 256, 0, stream>>>(hb, h, W1t + l * 65536, W2t + l * 65536, bufA);
        k_decomp<<<dim3(8, 128), 256, 0, stream>>>(bufA, h, hb);
    }
    k_ln<<<16384, 256, 0, stream>>>(h, lng, lnb, bufA);
    hipMemsetAsync(cm, 0, 16384 * sizeof(float), stream);
    k_colmean<<<dim3(8, 128), 128, 0, stream>>>(bufA, cm);
    hipMemsetAsync(d_out, 0, 128 * sizeof(float), stream);
    k_final<<<dim3(4, 128), 128, 0, stream>>>(bufA, cm, mark, pw, pb, out);

    (void)in_sizes; (void)n_in; (void)out_size; (void)ws_size;
}

// Round 4
// 658.523 us; speedup vs baseline: 2.0646x; 1.1269x over previous
//
#include <hip/hip_runtime.h>
#include <math.h>

#define DFF 512
#define NLAYER 2
#define TS_LD 132   // ts leading dim (bf16): 264B rows -> 2-way-free LDS writes

typedef __bf16 bf16x8 __attribute__((ext_vector_type(8)));
typedef __bf16 bf16x4 __attribute__((ext_vector_type(4)));
typedef float f32x4 __attribute__((ext_vector_type(4)));

__device__ __forceinline__ float4 f4_load(const float* p) { return *(const float4*)p; }
__device__ __forceinline__ void f4_store(float* p, float4 v) { *(float4*)p = v; }
__device__ __forceinline__ float4 f4_zero() { return make_float4(0.f, 0.f, 0.f, 0.f); }
__device__ __forceinline__ void f4_fma(float4& a, float s, const float4 w) {
    a.x += s * w.x; a.y += s * w.y; a.z += s * w.z; a.w += s * w.w;
}
__device__ __forceinline__ float gelu_f(float x) {
    return 0.5f * x * (1.0f + erff(x * 0.70710678118654752440f));
}
__device__ __forceinline__ void store_bf4(__bf16* p, float4 v) {
    __bf16 t[4] = {(__bf16)v.x, (__bf16)v.y, (__bf16)v.z, (__bf16)v.w};
    *(uint2*)p = *(uint2*)t;
}
__device__ __forceinline__ bf16x8 ld_b64x2(const __bf16* p) {
    bf16x4 lo = *(const bf16x4*)p;
    bf16x4 hi = *(const bf16x4*)(p + 4);
    return __builtin_shufflevector(lo, hi, 0, 1, 2, 3, 4, 5, 6, 7);
}

// ---------------------------------------------------------------------------
// Init: positional encoding fp32, Fttb bf16 [m2][t], Gtb bf16 [t][m2]
// (irfft scale folded into Gtb). Row 2m = cos, 2m+1 = -sin.
// ---------------------------------------------------------------------------
__global__ __launch_bounds__(256) void k_init(float* __restrict__ pe,
                                              __bf16* __restrict__ Fttb,
                                              __bf16* __restrict__ Gtb) {
    int idx = blockIdx.x * 256 + threadIdx.x;   // 0..65535
    {
        int l = idx >> 7, d = idx & 127;
        int j = d >> 1;
        double div = exp((double)(2 * j) * (-log(10000.0) / 128.0));
        double a = (double)l * div;
        pe[idx] = (d & 1) ? (float)cos(a) : (float)sin(a);
    }
    {
        int m2 = idx >> 9, t = idx & 511;
        int m = m2 >> 1;
        int r = (m * t) & 511;
        double ang = (double)r * (6.283185307179586476925287 / 512.0);
        float cv = (float)cos(ang), sv = (float)sin(ang);
        float f = (m2 & 1) ? -sv : cv;
        Fttb[idx] = (__bf16)f;
        float s = (m == 0) ? (1.0f / 512.0f) : (2.0f / 512.0f);
        Gtb[t * 128 + m2] = (__bf16)(f * s);
    }
}

// ---------------------------------------------------------------------------
// Cast+transpose weights to bf16: Wqt/Wot (n-major), W1t[f][k], W2t[n][f],
// plus conv weights cwtk[s][d][i] (n-major per shift).
// ---------------------------------------------------------------------------
__global__ __launch_bounds__(256) void k_castw(const float* __restrict__ Wq,
                                               const float* __restrict__ Wo,
                                               const float* __restrict__ W1,
                                               const float* __restrict__ W2,
                                               const float* __restrict__ cw,
                                               __bf16* __restrict__ wbf,
                                               __bf16* __restrict__ cwtk) {
    int i = blockIdx.x * 256 + threadIdx.x;   // < 376832
    if (i < 65536) {
        int r = i & 16383, l = (i >> 14) & 1;
        int n = r >> 7, k = r & 127;
        const float* W = (i >= 32768) ? Wo : Wq;
        wbf[i] = (__bf16)W[l * 16384 + k * 128 + n];
    } else if (i < 196608) {
        int j = i - 65536;
        int l = j >> 16, r = j & 65535;
        int f = r >> 7, k = r & 127;
        wbf[i] = (__bf16)W1[l * 65536 + k * 512 + f];
    } else if (i < 327680) {
        int j = i - 196608;
        int l = j >> 16, r = j & 65535;
        int n = r >> 9, f = r & 511;
        wbf[i] = (__bf16)W2[l * 65536 + f * 128 + n];
    } else if (i < 376832) {
        int j = i - 327680;          // s*16384 + d*128 + ii
        int s = j >> 14, r = j & 16383;
        int d = r >> 7, ii = r & 127;
        cwtk[j] = (__bf16)cw[(d * 128 + ii) * 3 + s];
    }
}

// ---------------------------------------------------------------------------
// Transpose x_enc (B,D,L) fp32 -> xt (B,L,D) bf16.
// ---------------------------------------------------------------------------
__global__ __launch_bounds__(256) void k_xpose(const float* __restrict__ xe,
                                               __bf16* __restrict__ xt) {
    __shared__ float ts[128][65];
    const int b = blockIdx.y, l0 = blockIdx.x * 64;
    for (int idx = threadIdx.x; idx < 128 * 16; idx += 256) {
        int d = idx >> 4, c4 = idx & 15;
        float4 v = f4_load(&xe[((size_t)b * 128 + d) * 512 + l0 + c4 * 4]);
        ts[d][c4 * 4 + 0] = v.x; ts[d][c4 * 4 + 1] = v.y;
        ts[d][c4 * 4 + 2] = v.z; ts[d][c4 * 4 + 3] = v.w;
    }
    __syncthreads();
#pragma unroll
    for (int p = 0; p < 4; ++p) {
        int l = (threadIdx.x >> 4) + p * 16;
        int d0 = (threadIdx.x & 15) * 8;
        __bf16 tmp[8];
#pragma unroll
        for (int j = 0; j < 8; ++j) tmp[j] = (__bf16)ts[d0 + j][l];
        *(uint4*)&xt[((size_t)b * 512 + l0 + l) * 128 + d0] = *(uint4*)tmp;
    }
}

// ---------------------------------------------------------------------------
// MFMA embed: h[b,l,d] = sum_s sum_i xt[b,(l-1+s)%512,i]*cwtk[s][d][i] + pe.
// ---------------------------------------------------------------------------
__global__ __launch_bounds__(256) void k_embed_m(const __bf16* __restrict__ xt,
                                                 const __bf16* __restrict__ cwtk,
                                                 const float* __restrict__ pe,
                                                 float* __restrict__ h,
                                                 __bf16* __restrict__ hb) {
    __shared__ __align__(16) __bf16 xs[130 * 128];
    const int b = blockIdx.x >> 2, l0 = (blockIdx.x & 3) * 128;
    for (int c = threadIdx.x; c < 130 * 16; c += 256) {
        int r = c >> 4, g = c & 15;
        int gl = (l0 - 1 + r) & 511;
        *(uint4*)&xs[(r << 7) + ((g ^ (r & 7)) << 3)] =
            *(const uint4*)&xt[(((size_t)b * 512 + gl) << 7) + (g << 3)];
    }
    __syncthreads();
    const int lane = threadIdx.x & 63, wid = threadIdx.x >> 6;
    const int wrow = (wid & 1) * 64, wcol = (wid >> 1) * 64;
    const int m16 = lane & 15, quad = lane >> 4;
    f32x4 acc[4][4];
#pragma unroll
    for (int a = 0; a < 4; ++a)
#pragma unroll
        for (int bb = 0; bb < 4; ++bb) acc[a][bb] = {0.f, 0.f, 0.f, 0.f};
#pragma unroll
    for (int s = 0; s < 3; ++s) {
#pragma unroll
        for (int ks = 0; ks < 4; ++ks) {
            const int ko = ks * 32 + quad * 8;
            bf16x8 af[4], bfr[4];
#pragma unroll
            for (int rt = 0; rt < 4; ++rt) {
                int r = wrow + rt * 16 + m16 + s;
                af[rt] = *(const bf16x8*)&xs[(r << 7) + (((ks * 4 + quad) ^ (r & 7)) << 3)];
            }
#pragma unroll
            for (int ct = 0; ct < 4; ++ct)
                bfr[ct] = *(const bf16x8*)&cwtk[((size_t)(s * 128 + wcol + ct * 16 + m16) << 7) + ko];
#pragma unroll
            for (int rt = 0; rt < 4; ++rt)
#pragma unroll
                for (int ct = 0; ct < 4; ++ct)
                    acc[rt][ct] = __builtin_amdgcn_mfma_f32_16x16x32_bf16(
                        af[rt], bfr[ct], acc[rt][ct], 0, 0, 0);
        }
    }
#pragma unroll
    for (int ct = 0; ct < 4; ++ct) {
        int gcol = wcol + ct * 16 + m16;
#pragma unroll
        for (int rt = 0; rt < 4; ++rt)
#pragma unroll
            for (int r = 0; r < 4; ++r) {
                int l = l0 + wrow + rt * 16 + quad * 4 + r;
                float v = acc[rt][ct][r] + pe[l * 128 + gcol];
                size_t gi = (((size_t)b * 512 + l) << 7) + gcol;
                h[gi] = v;
                hb[gi] = (__bf16)v;
            }
    }
}

// ---------------------------------------------------------------------------
// q-proj transposed: qT[n][row] = (X @ Wq + bq)^T, bf16 out.
// A = Wqt rows (n-major, k-contig), B = X rows (k-contig) -> D[n][row].
// ---------------------------------------------------------------------------
__global__ __launch_bounds__(256) void k_qprojT(const __bf16* __restrict__ Xb,
                                                const __bf16* __restrict__ Wt,
                                                const float* __restrict__ bias,
                                                __bf16* __restrict__ qT) {
    __shared__ __align__(16) __bf16 xs[128 * 128];
    const int rowBase = blockIdx.x * 128;
#pragma unroll
    for (int i = 0; i < 8; ++i) {
        int c = i * 256 + threadIdx.x;
        int r = c >> 4, g = c & 15;
        *(uint4*)&xs[(r << 7) + ((g ^ (r & 7)) << 3)] =
            *(const uint4*)&Xb[(((size_t)rowBase + r) << 7) + (g << 3)];
    }
    __syncthreads();
    const int lane = threadIdx.x & 63, wid = threadIdx.x >> 6;
    const int wn = (wid & 1) * 64, wr = (wid >> 1) * 64;
    const int m16 = lane & 15, quad = lane >> 4;
    f32x4 acc[4][4];
#pragma unroll
    for (int a = 0; a < 4; ++a)
#pragma unroll
        for (int b = 0; b < 4; ++b) acc[a][b] = {0.f, 0.f, 0.f, 0.f};
#pragma unroll
    for (int ks = 0; ks < 4; ++ks) {
        const int ko = ks * 32 + quad * 8;
        bf16x8 wf[4], xf[4];
#pragma unroll
        for (int rt = 0; rt < 4; ++rt)
            wf[rt] = *(const bf16x8*)&Wt[((size_t)(wn + rt * 16 + m16) << 7) + ko];
#pragma unroll
        for (int ct = 0; ct < 4; ++ct) {
            int r = wr + ct * 16 + m16;
            xf[ct] = *(const bf16x8*)&xs[(r << 7) + (((ks * 4 + quad) ^ (r & 7)) << 3)];
        }
#pragma unroll
        for (int rt = 0; rt < 4; ++rt)
#pragma unroll
            for (int ct = 0; ct < 4; ++ct)
                acc[rt][ct] = __builtin_amdgcn_mfma_f32_16x16x32_bf16(
                    wf[rt], xf[ct], acc[rt][ct], 0, 0, 0);
    }
#pragma unroll
    for (int rt = 0; rt < 4; ++rt)
#pragma unroll
        for (int r = 0; r < 4; ++r) {
            int n = wn + rt * 16 + quad * 4 + r;
            float bv = bias[n];
#pragma unroll
            for (int ct = 0; ct < 4; ++ct) {
                int grow = rowBase + wr + ct * 16 + m16;
                qT[(size_t)n * 65536 + grow] = (__bf16)(acc[rt][ct][r] + bv);
            }
        }
}

// ---------------------------------------------------------------------------
// Forward DFT via MFMA: c[b][d][m2] = sum_t qT[d][b*512+t] * Fttb[m2][t].
// Both operands row-major k(t)-contiguous: no LDS, no barriers.
// Block: 128 threads = 2 waves (m2 halves); blockIdx.x = d-half, .y = b.
// ---------------------------------------------------------------------------
__global__ __launch_bounds__(128) void k_fdft_m(const __bf16* __restrict__ qT,
                                                const __bf16* __restrict__ Fttb,
                                                float* __restrict__ c) {
    const int b = blockIdx.y, d0 = blockIdx.x * 64;
    const int lane = threadIdx.x & 63, wid = threadIdx.x >> 6;
    const int wm = wid * 64;
    const int m16 = lane & 15, quad = lane >> 4;
    f32x4 acc[4][4];
#pragma unroll
    for (int a = 0; a < 4; ++a)
#pragma unroll
        for (int bb = 0; bb < 4; ++bb) acc[a][bb] = {0.f, 0.f, 0.f, 0.f};
    for (int ks = 0; ks < 16; ++ks) {
        const int ko = ks * 32 + quad * 8;
        bf16x8 af[4], bf[4];
#pragma unroll
        for (int rt = 0; rt < 4; ++rt)
            af[rt] = *(const bf16x8*)&qT[(size_t)(d0 + rt * 16 + m16) * 65536 + b * 512 + ko];
#pragma unroll
        for (int ct = 0; ct < 4; ++ct)
            bf[ct] = *(const bf16x8*)&Fttb[(size_t)(wm + ct * 16 + m16) * 512 + ko];
#pragma unroll
        for (int rt = 0; rt < 4; ++rt)
#pragma unroll
            for (int ct = 0; ct < 4; ++ct)
                acc[rt][ct] = __builtin_amdgcn_mfma_f32_16x16x32_bf16(
                    af[rt], bf[ct], acc[rt][ct], 0, 0, 0);
    }
#pragma unroll
    for (int ct = 0; ct < 4; ++ct) {
        int m2 = wm + ct * 16 + m16;
#pragma unroll
        for (int rt = 0; rt < 4; ++rt)
#pragma unroll
            for (int r = 0; r < 4; ++r) {
                int d = d0 + rt * 16 + quad * 4 + r;
                c[((size_t)b * 128 + d) * 128 + m2] = acc[rt][ct][r];
            }
    }
}

// ---------------------------------------------------------------------------
// Mode mix (fp32 in, bf16 out): complex 16-vec x 16x16 per (b,h,m).
// ---------------------------------------------------------------------------
__global__ __launch_bounds__(256) void k_mix(const float* __restrict__ cbuf,
                                             const float* __restrict__ fwr,
                                             const float* __restrict__ fwi,
                                             __bf16* __restrict__ ddb) {
    __shared__ float cs[16][128];
    const int hh = blockIdx.x, b = blockIdx.y;
    for (int idx = threadIdx.x; idx < 16 * 32; idx += 256) {
        int e = idx >> 5, c4 = idx & 31;
        f4_store(&cs[e][c4 * 4],
                 f4_load(&cbuf[((size_t)b * 128 + hh * 16 + e) * 128 + c4 * 4]));
    }
    __syncthreads();
    const int m = threadIdx.x & 63, og = threadIdx.x >> 6;
    float dr[4] = {0.f, 0.f, 0.f, 0.f}, di[4] = {0.f, 0.f, 0.f, 0.f};
    for (int e = 0; e < 16; ++e) {
        float2 cv = *(const float2*)&cs[e][2 * m];
#pragma unroll
        for (int oi = 0; oi < 4; ++oi) {
            int o = og * 4 + oi;
            float wr = fwr[(((size_t)hh * 16 + e) * 16 + o) * 64 + m];
            float wi = fwi[(((size_t)hh * 16 + e) * 16 + o) * 64 + m];
            dr[oi] += cv.x * wr - cv.y * wi;
            di[oi] += cv.x * wi + cv.y * wr;
        }
    }
#pragma unroll
    for (int oi = 0; oi < 4; ++oi) {
        int o = og * 4 + oi;
        __bf16 t2[2] = {(__bf16)dr[oi], (__bf16)di[oi]};
        *(uint*)&ddb[((size_t)b * 128 + hh * 16 + o) * 128 + 2 * m] = *(uint*)t2;
    }
}

// ---------------------------------------------------------------------------
// Inverse DFT via MFMA: y[b][ho][t] = sum_m2 Gtb[t][m2] * ddb[b][ho][m2].
// A = Gtb rows (t), B = ddb rows (ho); D rows = t -> 4-consecutive-t 8B stores
// into the flat (B,H*E,L) buffer. No LDS, no barriers.
// ---------------------------------------------------------------------------
__global__ __launch_bounds__(256) void k_idft_m(const __bf16* __restrict__ ddb,
                                                const __bf16* __restrict__ Gtb,
                                                __bf16* __restrict__ y) {
    const int b = blockIdx.y, t0 = blockIdx.x * 128;
    const int lane = threadIdx.x & 63, wid = threadIdx.x >> 6;
    const int wt = (wid & 1) * 64, wh = (wid >> 1) * 64;
    const int m16 = lane & 15, quad = lane >> 4;
    f32x4 acc[4][4];
#pragma unroll
    for (int a = 0; a < 4; ++a)
#pragma unroll
        for (int bb = 0; bb < 4; ++bb) acc[a][bb] = {0.f, 0.f, 0.f, 0.f};
#pragma unroll
    for (int ks = 0; ks < 4; ++ks) {
        const int ko = ks * 32 + quad * 8;
        bf16x8 af[4], bf[4];
#pragma unroll
        for (int rt = 0; rt < 4; ++rt)
            af[rt] = *(const bf16x8*)&Gtb[(size_t)(t0 + wt + rt * 16 + m16) * 128 + ko];
#pragma unroll
        for (int ct = 0; ct < 4; ++ct)
            bf[ct] = *(const bf16x8*)&ddb[((size_t)b * 128 + wh + ct * 16 + m16) * 128 + ko];
#pragma unroll
        for (int rt = 0; rt < 4; ++rt)
#pragma unroll
            for (int ct = 0; ct < 4; ++ct)
                acc[rt][ct] = __builtin_amdgcn_mfma_f32_16x16x32_bf16(
                    af[rt], bf[ct], acc[rt][ct], 0, 0, 0);
    }
#pragma unroll
    for (int rt = 0; rt < 4; ++rt)
#pragma unroll
        for (int ct = 0; ct < 4; ++ct) {
            int ho = wh + ct * 16 + m16;
            int tb = t0 + wt + rt * 16 + quad * 4;
            __bf16 tmp[4] = {(__bf16)acc[rt][ct][0], (__bf16)acc[rt][ct][1],
                             (__bf16)acc[rt][ct][2], (__bf16)acc[rt][ct][3]};
            *(uint2*)&y[((size_t)b * 128 + ho) * 512 + tb] = *(uint2*)tmp;
        }
}

// ---------------------------------------------------------------------------
// MFMA GEMM: out(M x 128 fp32) = Xb(M x 128 bf16) @ W(128x128) + bias (+R).
// ---------------------------------------------------------------------------
template <bool RES>
__global__ __launch_bounds__(256) void k_mgemm(const __bf16* __restrict__ Xb,
                                               const __bf16* __restrict__ Wt,
                                               const float* __restrict__ bias,
                                               const float* __restrict__ R,
                                               float* __restrict__ out) {
    __shared__ __align__(16) __bf16 xs[128 * 128];
    const int rowBase = blockIdx.x * 128;
#pragma unroll
    for (int i = 0; i < 8; ++i) {
        int c = i * 256 + threadIdx.x;
        int r = c >> 4, g = c & 15;
        *(uint4*)&xs[(r << 7) + ((g ^ (r & 7)) << 3)] =
            *(const uint4*)&Xb[(((size_t)rowBase + r) << 7) + (g << 3)];
    }
    __syncthreads();
    const int lane = threadIdx.x & 63, wid = threadIdx.x >> 6;
    const int wrow = (wid & 1) * 64, wcol = (wid >> 1) * 64;
    const int m16 = lane & 15, quad = lane >> 4;
    f32x4 acc[4][4];
#pragma unroll
    for (int a = 0; a < 4; ++a)
#pragma unroll
        for (int b = 0; b < 4; ++b) acc[a][b] = {0.f, 0.f, 0.f, 0.f};
#pragma unroll
    for (int ks = 0; ks < 4; ++ks) {
        const int ko = ks * 32 + quad * 8;
        const int xg = (((ks * 4 + quad) ^ (m16 & 7)) << 3);
        bf16x8 af[4], bfr[4];
#pragma unroll
        for (int rt = 0; rt < 4; ++rt)
            af[rt] = *(const bf16x8*)&xs[((wrow + rt * 16 + m16) << 7) + xg];
#pragma unroll
        for (int ct = 0; ct < 4; ++ct)
            bfr[ct] = *(const bf16x8*)&Wt[((size_t)(wcol + ct * 16 + m16) << 7) + ko];
#pragma unroll
        for (int rt = 0; rt < 4; ++rt)
#pragma unroll
            for (int ct = 0; ct < 4; ++ct)
                acc[rt][ct] = __builtin_amdgcn_mfma_f32_16x16x32_bf16(
                    af[rt], bfr[ct], acc[rt][ct], 0, 0, 0);
    }
#pragma unroll
    for (int ct = 0; ct < 4; ++ct) {
        int gcol = wcol + ct * 16 + m16;
        float bv = bias[gcol];
#pragma unroll
        for (int rt = 0; rt < 4; ++rt)
#pragma unroll
            for (int r = 0; r < 4; ++r) {
                size_t gi = ((size_t)(rowBase + wrow + rt * 16 + quad * 4 + r) << 7) + gcol;
                float v = acc[rt][ct][r] + bv;
                if (RES) v += R[gi];
                out[gi] = v;
            }
    }
}

// ---------------------------------------------------------------------------
// MFMA FFN: out = Xf + gelu(X @ W1) @ W2. ts stride 132 -> 2-way-free writes.
// ---------------------------------------------------------------------------
__global__ __launch_bounds__(256) void k_ffnm(const __bf16* __restrict__ Xb,
                                              const float* __restrict__ Xf,
                                              const __bf16* __restrict__ W1t,
                                              const __bf16* __restrict__ W2t,
                                              float* __restrict__ out) {
    __shared__ __align__(16) __bf16 xs[128 * 128];
    __shared__ __align__(16) __bf16 ts[128 * TS_LD];
    const int rowBase = blockIdx.x * 128;
#pragma unroll
    for (int i = 0; i < 8; ++i) {
        int c = i * 256 + threadIdx.x;
        int r = c >> 4, g = c & 15;
        *(uint4*)&xs[(r << 7) + ((g ^ (r & 7)) << 3)] =
            *(const uint4*)&Xb[(((size_t)rowBase + r) << 7) + (g << 3)];
    }
    __syncthreads();
    const int lane = threadIdx.x & 63, wid = threadIdx.x >> 6;
    const int wrow = (wid & 1) * 64, wcol = (wid >> 1) * 64;
    const int m16 = lane & 15, quad = lane >> 4;
    f32x4 acc2[4][4];
#pragma unroll
    for (int a = 0; a < 4; ++a)
#pragma unroll
        for (int b = 0; b < 4; ++b) acc2[a][b] = {0.f, 0.f, 0.f, 0.f};

    for (int f0 = 0; f0 < DFF; f0 += 128) {
        f32x4 c1[4][4];
#pragma unroll
        for (int a = 0; a < 4; ++a)
#pragma unroll
            for (int b = 0; b < 4; ++b) c1[a][b] = {0.f, 0.f, 0.f, 0.f};
#pragma unroll
        for (int ks = 0; ks < 4; ++ks) {
            const int ko = ks * 32 + quad * 8;
            const int xg = (((ks * 4 + quad) ^ (m16 & 7)) << 3);
            bf16x8 af[4], bfr[4];
#pragma unroll
            for (int rt = 0; rt < 4; ++rt)
                af[rt] = *(const bf16x8*)&xs[((wrow + rt * 16 + m16) << 7) + xg];
#pragma unroll
            for (int ct = 0; ct < 4; ++ct)
                bfr[ct] = *(const bf16x8*)&W1t[((size_t)(f0 + wcol + ct * 16 + m16) << 7) + ko];
#pragma unroll
            for (int rt = 0; rt < 4; ++rt)
#pragma unroll
                for (int ct = 0; ct < 4; ++ct)
                    c1[rt][ct] = __builtin_amdgcn_mfma_f32_16x16x32_bf16(
                        af[rt], bfr[ct], c1[rt][ct], 0, 0, 0);
        }
#pragma unroll
        for (int rt = 0; rt < 4; ++rt)
#pragma unroll
            for (int ct = 0; ct < 4; ++ct)
#pragma unroll
                for (int r = 0; r < 4; ++r) {
                    int lrow = wrow + rt * 16 + quad * 4 + r;
                    int lcol = wcol + ct * 16 + m16;
                    ts[lrow * TS_LD + lcol] = (__bf16)gelu_f(c1[rt][ct][r]);
                }
        __syncthreads();
#pragma unroll
        for (int ks = 0; ks < 4; ++ks) {
            const int ko = ks * 32 + quad * 8;
            bf16x8 af[4], bfr[4];
#pragma unroll
            for (int rt = 0; rt < 4; ++rt)
                af[rt] = ld_b64x2(&ts[(wrow + rt * 16 + m16) * TS_LD + ko]);
#pragma unroll
            for (int ct = 0; ct < 4; ++ct)
                bfr[ct] = *(const bf16x8*)&W2t[((size_t)(wcol + ct * 16 + m16) << 9) + f0 + ko];
#pragma unroll
            for (int rt = 0; rt < 4; ++rt)
#pragma unroll
                for (int ct = 0; ct < 4; ++ct)
                    acc2[rt][ct] = __builtin_amdgcn_mfma_f32_16x16x32_bf16(
                        af[rt], bfr[ct], acc2[rt][ct], 0, 0, 0);
        }
        __syncthreads();
    }
#pragma unroll
    for (int ct = 0; ct < 4; ++ct) {
        int gcol = wcol + ct * 16 + m16;
#pragma unroll
        for (int rt = 0; rt < 4; ++rt)
#pragma unroll
            for (int r = 0; r < 4; ++r) {
                size_t gi = ((size_t)(rowBase + wrow + rt * 16 + quad * 4 + r) << 7) + gcol;
                out[gi] = acc2[rt][ct][r] + Xf[gi];
            }
    }
}

// ---------------------------------------------------------------------------
// Series decomp: out = x - movmean(x,25); writes fp32 + bf16 shadow.
// ---------------------------------------------------------------------------
__global__ __launch_bounds__(256) void k_decomp(const float* __restrict__ X,
                                                float* __restrict__ out,
                                                __bf16* __restrict__ outb) {
    __shared__ float xs[88][128];
    const int b = blockIdx.y, l0 = blockIdx.x * 64;
    for (int idx = threadIdx.x; idx < 88 * 32; idx += 256) {
        int r = idx >> 5, c4 = idx & 31;
        int gl = l0 - 12 + r;
        gl = gl < 0 ? 0 : (gl > 511 ? 511 : gl);
        f4_store(&xs[r][c4 * 4], f4_load(&X[((size_t)b * 512 + gl) * 128 + c4 * 4]));
    }
    __syncthreads();
    const int dg = threadIdx.x & 31, lg = threadIdx.x >> 5;
    const int d0 = dg * 4, base = lg * 8;
    float4 s = f4_zero();
#pragma unroll
    for (int w = 0; w < 25; ++w) {
        float4 v = f4_load(&xs[base + w][d0]);
        s.x += v.x; s.y += v.y; s.z += v.z; s.w += v.w;
    }
    const float inv = 1.0f / 25.0f;
#pragma unroll
    for (int i = 0; i < 8; ++i) {
        int t = base + 12 + i;
        float4 x = f4_load(&xs[t][d0]);
        float4 o = make_float4(x.x - s.x * inv, x.y - s.y * inv,
                               x.z - s.z * inv, x.w - s.w * inv);
        size_t gi = ((size_t)b * 512 + l0 + lg * 8 + i) * 128 + d0;
        f4_store(&out[gi], o);
        store_bf4(&outb[gi], o);
        if (i < 7) {
            float4 a = f4_load(&xs[base + 25 + i][d0]);
            float4 r = f4_load(&xs[base + i][d0]);
            s.x += a.x - r.x; s.y += a.y - r.y; s.z += a.z - r.z; s.w += a.w - r.w;
        }
    }
}

// ---------------------------------------------------------------------------
// LayerNorm over D=128; one wave per row.
// ---------------------------------------------------------------------------
__global__ __launch_bounds__(256) void k_ln(const float* __restrict__ X,
                                            const float* __restrict__ g,
                                            const float* __restrict__ bb,
                                            float* __restrict__ out) {
    const int row = blockIdx.x * 4 + (threadIdx.x >> 6);
    const int lane = threadIdx.x & 63;
    float2 v = *(const float2*)&X[(size_t)row * 128 + lane * 2];
    float s = v.x + v.y, ss = v.x * v.x + v.y * v.y;
#pragma unroll
    for (int o = 32; o; o >>= 1) {
        s += __shfl_xor(s, o);
        ss += __shfl_xor(ss, o);
    }
    float mu = s * (1.0f / 128.0f);
    float var = ss * (1.0f / 128.0f) - mu * mu;
    float rstd = rsqrtf(var + 1e-5f);
    float2 gg = *(const float2*)&g[lane * 2];
    float2 bv = *(const float2*)&bb[lane * 2];
    float2 o;
    o.x = (v.x - mu) * rstd * gg.x + bv.x;
    o.y = (v.y - mu) * rstd * gg.y + bv.y;
    *(float2*)&out[(size_t)row * 128 + lane * 2] = o;
}

__global__ __launch_bounds__(128) void k_colmean(const float* __restrict__ X,
                                                 float* __restrict__ cm) {
    const int b = blockIdx.y, l0 = blockIdx.x * 64, d = threadIdx.x;
    float s = 0.f;
    for (int l = l0; l < l0 + 64; ++l) s += X[((size_t)b * 512 + l) * 128 + d];
    atomicAdd(&cm[b * 128 + d], s);
}

__global__ __launch_bounds__(128) void k_final(const float* __restrict__ hn,
                                               const float* __restrict__ cm,
                                               const float* __restrict__ mark,
                                               const float* __restrict__ pw,
                                               const float* __restrict__ pb,
                                               float* __restrict__ out) {
    const int b = blockIdx.y, l0 = blockIdx.x * 128, d = threadIdx.x;
    const float c = cm[b * 128 + d] * (1.0f / 512.0f);
    float acc = 0.f;
    for (int l = l0; l < l0 + 128; ++l) {
        float v = hn[((size_t)b * 512 + l) * 128 + d] - c;
        acc += gelu_f(v) * mark[((size_t)b * 128 + d) * 512 + l] * pw[l * 128 + d];
    }
    __shared__ float red[2];
#pragma unroll
    for (int o = 32; o; o >>= 1) acc += __shfl_xor(acc, o);
    if ((threadIdx.x & 63) == 0) red[threadIdx.x >> 6] = acc;
    __syncthreads();
    if (threadIdx.x == 0) {
        float tot = red[0] + red[1];
        if (blockIdx.x == 0) tot += pb[0];
        atomicAdd(&out[b], tot);
    }
}

// ---------------------------------------------------------------------------
extern "C" void kernel_launch(void* const* d_in, const int* in_sizes, int n_in,
                              void* d_out, int out_size, void* d_ws, size_t ws_size,
                              hipStream_t stream) {
    const float* xe   = (const float*)d_in[0];
    const float* mark = (const float*)d_in[1];
    const float* cw   = (const float*)d_in[4];
    const float* Wq   = (const float*)d_in[5];
    const float* bq   = (const float*)d_in[6];
    const float* Wo   = (const float*)d_in[7];
    const float* bo   = (const float*)d_in[8];
    const float* fwr  = (const float*)d_in[9];
    const float* fwi  = (const float*)d_in[10];
    const float* W1   = (const float*)d_in[11];
    const float* W2   = (const float*)d_in[12];
    const float* lng  = (const float*)d_in[13];
    const float* lnb  = (const float*)d_in[14];
    const float* pw   = (const float*)d_in[15];
    const float* pb   = (const float*)d_in[16];
    float* out = (float*)d_out;

    // Workspace layout (float-slot offsets). Total ~101.9 MB.
    float* ws    = (float*)d_ws;
    __bf16* Fttb = (__bf16*)ws;              // 65536 bf16 in [0,65536) slots
    __bf16* Gtb  = (__bf16*)(ws + 65536);    // 65536 bf16
    float* h     = ws + 131072;              // 8388608 fp32 state
    float* bufA  = ws + 8519680;             // 8388608 (xt | qT+ddb | s | hn)
    __bf16* hb   = (__bf16*)(ws + 16908288); // 8388608 bf16
    float* yrg   = ws + 21102592;            // 4194304 (pe+cwtk | c | yb)
    float* cm    = ws + 25296896;            // 16384
    __bf16* wbf  = (__bf16*)(ws + 25313280); // 327680 bf16
    float* pe    = yrg;                      // [0,65536) of yrg
    __bf16* cwtk = (__bf16*)(yrg + 65536);   // 49152 bf16 (dead after embed)
    float* cbuf  = yrg;                      // c (dead after mix)
    __bf16* yb   = (__bf16*)yrg;             // overlays c
    __bf16* xt   = (__bf16*)bufA;            // dead after embed
    __bf16* qT   = (__bf16*)bufA;            // 8388608 bf16 (dead after fdft)
    __bf16* ddb  = (__bf16*)(bufA + 4194304);// 2097152 bf16
    __bf16* Wqt  = wbf;
    __bf16* Wot  = wbf + 32768;
    __bf16* W1t  = wbf + 65536;
    __bf16* W2t  = wbf + 196608;

    k_init<<<256, 256, 0, stream>>>(pe, Fttb, Gtb);
    k_castw<<<1472, 256, 0, stream>>>(Wq, Wo, W1, W2, cw, wbf, cwtk);
    k_xpose<<<dim3(8, 128), 256, 0, stream>>>(xe, xt);
    k_embed_m<<<512, 256, 0, stream>>>(xt, cwtk, pe, h, hb);
    for (int l = 0; l < NLAYER; ++l) {
        k_qprojT<<<512, 256, 0, stream>>>(hb, Wqt + l * 16384, bq + l * 128, qT);
        k_fdft_m<<<dim3(2, 128), 128, 0, stream>>>(qT, Fttb, cbuf);
        k_mix<<<dim3(8, 128), 256, 0, stream>>>(cbuf, fwr + l * 131072,
                                                fwi + l * 131072, ddb);
        k_idft_m<<<dim3(4, 128), 256, 0, stream>>>(ddb, Gtb, yb);
        k_mgemm<true><<<512, 256, 0, stream>>>(yb, Wot + l * 16384, bo + l * 128,
                                               h, bufA);
        k_decomp<<<dim3(8, 128), 256, 0, stream>>>(bufA, h, hb);
        k_ffnm<<<512, 256, 0, stream>>>(hb, h, W1t + l * 65536, W2t + l * 65536, bufA);
        k_decomp<<<dim3(8, 128), 256, 0, stream>>>(bufA, h, hb);
    }
    k_ln<<<16384, 256, 0, stream>>>(h, lng, lnb, bufA);
    hipMemsetAsync(cm, 0, 16384 * sizeof(float), stream);
    k_colmean<<<dim3(8, 128), 128, 0, stream>>>(bufA, cm);
    hipMemsetAsync(d_out, 0, 128 * sizeof(float), stream);
    k_final<<<dim3(4, 128), 128, 0, stream>>>(bufA, cm, mark, pw, pb, out);

    (void)in_sizes; (void)n_in; (void)out_size; (void)ws_size;
}